// Round 3
// baseline (1241.480 us; speedup 1.0000x reference)
//
#include <hip/hip_runtime.h>
#include <math.h>

#define N_ 5
#define A_ 900
#define AD_ 8
#define D_ 256
#define H_ 8
#define DH_ 32
#define K_ 300
#define NM1_ 4
#define M_ 1200  // K_*(N_-1)

// attention tiling
#define QT2_ 32   // queries per block
#define NG_ 8     // m-groups per block
#define GM_ 150   // m per group
#define MC2_ 15   // m-chunk per LDS stage
#define NCH_ 10   // chunks per group

typedef _Float16 f16x8 __attribute__((ext_vector_type(8)));
typedef float f32x4 __attribute__((ext_vector_type(4)));

// ---------------- scores: sigmoid(b_feature @ w_roi + b_roi) ----------------
__global__ __launch_bounds__(256) void score_kernel(const float* __restrict__ bf,
                                                    const float* __restrict__ w,
                                                    const float* __restrict__ b,
                                                    float* __restrict__ scores) {
  int wid = threadIdx.x >> 6, lane = threadIdx.x & 63;
  int row = blockIdx.x * 4 + wid;
  if (row >= N_ * A_) return;
  const float* x = bf + (long)row * D_;
  float dot = 0.f;
#pragma unroll
  for (int t = 0; t < 4; t++) dot += x[lane + 64 * t] * w[lane + 64 * t];
#pragma unroll
  for (int o = 32; o; o >>= 1) dot += __shfl_xor(dot, o, 64);
  if (lane == 0) scores[row] = 1.0f / (1.0f + expf(-(dot + b[0])));
}

// ---------------- top-k via bitonic sort (1 block per batch row) ----------------
__global__ __launch_bounds__(1024) void topk_kernel(const float* __restrict__ scores,
                                                    int* __restrict__ top_idx,
                                                    float* __restrict__ conf) {
  __shared__ float sc[1024];
  __shared__ int si[1024];
  int i = blockIdx.x, t = threadIdx.x;
  sc[t] = (t < A_) ? scores[i * A_ + t] : -INFINITY;
  si[t] = t;
  __syncthreads();
  for (int k = 2; k <= 1024; k <<= 1) {
    for (int j = k >> 1; j > 0; j >>= 1) {
      int ixj = t ^ j;
      if (ixj > t) {
        bool dir = ((t & k) == 0);
        float a = sc[t], b = sc[ixj];
        bool sw = dir ? (a < b) : (a > b);
        if (sw) {
          sc[t] = b; sc[ixj] = a;
          int tmp = si[t]; si[t] = si[ixj]; si[ixj] = tmp;
        }
      }
      __syncthreads();
    }
  }
  if (t < K_) {
    top_idx[i * K_ + t] = si[t];
    conf[i * K_ + t] = sc[t] > 0.5f ? 1.0f : 0.0f;
  }
}

// ---------------- tiny MLP: one block per transform row ----------------
__global__ __launch_bounds__(256) void mlp_kernel(const float* __restrict__ tm,
                                                  const float* __restrict__ bn_g, const float* __restrict__ bn_b,
                                                  const float* __restrict__ fc1_w, const float* __restrict__ fc1_b,
                                                  const float* __restrict__ fc2_w, const float* __restrict__ fc2_b,
                                                  float* __restrict__ t_out) {
  int r = blockIdx.x;  // 0..19
  int t = threadIdx.x;
  __shared__ float x[20][12];
  __shared__ float y[12];
  __shared__ float hbuf[D_];
  if (t < 240) {
    int rr = t / 12, f = t % 12;
    int i = rr / NM1_, jj = rr % NM1_;
    int j = jj < i ? jj : jj + 1;
    int r4 = f / 4, c4 = f % 4;
    x[rr][f] = tm[((long)(i * N_ + j) * 4 + r4) * 4 + c4];
  }
  __syncthreads();
  if (t < 12) {
    float s = 0.f;
    for (int rr = 0; rr < 20; rr++) s += x[rr][t];
    float m = s / 20.0f;
    float v = 0.f;
    for (int rr = 0; rr < 20; rr++) { float d = x[rr][t] - m; v += d * d; }
    v /= 20.0f;
    y[t] = (x[r][t] - m) * rsqrtf(v + 1e-5f) * bn_g[t] + bn_b[t];
  }
  __syncthreads();
  float acc = fc1_b[t];
#pragma unroll
  for (int f = 0; f < 12; f++) acc += y[f] * fc1_w[f * D_ + t];
  hbuf[t] = fmaxf(acc, 0.0f);
  __syncthreads();
  float acc2 = fc2_b[t];
  for (int k = 0; k < D_; k++) acc2 += hbuf[k] * fc2_w[k * D_ + t];
  t_out[r * D_ + t] = acc2;
}

// ---------------- bbox min/max ----------------
__global__ void bbox_kernel(const float* __restrict__ ban, float* __restrict__ mn, float* __restrict__ mx) {
  int idx = blockIdx.x * blockDim.x + threadIdx.x;
  if (idx >= N_ * A_) return;
  const float* a = ban + (long)idx * AD_;
  float x = a[0], y = a[1], z = a[2];
  float w = expf(a[3]), l = expf(a[4]), h = expf(a[5]);
  float yaw = atan2f(a[6], a[7]);
  float ca = fabsf(cosf(yaw)), sa = fabsf(sinf(yaw));
  float ex = 0.5f * (l * ca + w * sa);
  float ey = 0.5f * (l * sa + w * ca);
  float ez = 0.5f * h;
  mn[idx * 3 + 0] = x - ex; mn[idx * 3 + 1] = y - ey; mn[idx * 3 + 2] = z - ez;
  mx[idx * 3 + 0] = x + ex; mx[idx * 3 + 1] = y + ey; mx[idx * 3 + 2] = z + ez;
}

// ---------------- gather: key_feat, i2j_rm, conf_rm, key_in (k-parallel) ----------------
#define GKT_ 60  // k per block
__global__ __launch_bounds__(256) void gather_kernel(const float* __restrict__ b_feature,
                                                     const float* __restrict__ i2j_anchor,
                                                     const int* __restrict__ top_idx,
                                                     const float* __restrict__ conf,
                                                     const float* __restrict__ anc_w,
                                                     const float* __restrict__ anc_b,
                                                     const float* __restrict__ t_mlp,
                                                     float* __restrict__ key_feat,
                                                     float* __restrict__ conf_rm,
                                                     float* __restrict__ i2j_rm,
                                                     float* __restrict__ key_in) {
  int blk = blockIdx.x;  // i*4+jj
  int i = blk / NM1_, jj = blk % NM1_;
  int j = jj < i ? jj : jj + 1;
  int k0 = blockIdx.y * GKT_;
  int c = threadIdx.x;
  __shared__ float aw[AD_][D_];
#pragma unroll
  for (int r = 0; r < AD_; r++) aw[r][c] = anc_w[r * D_ + c];
  float ab = anc_b[c];
  float tv = t_mlp[(i * NM1_ + jj) * D_ + c];
  __syncthreads();
  for (int k = k0; k < k0 + GKT_; k++) {
    int idx = top_idx[j * K_ + k];
    float cf = conf[j * K_ + k];
    const float* src = b_feature + ((long)(j * A_ + idx)) * D_;
    float val = src[c];
    long mrow = (long)i * M_ + jj * K_ + k;
    key_feat[mrow * D_ + c] = val;
    const float* ap = i2j_anchor + ((long)((i * N_ + j) * A_ + idx)) * AD_;
    if (c < AD_) i2j_rm[mrow * AD_ + c] = ap[c];
    if (c == 0) conf_rm[mrow] = cf;
    float pos = ab + tv;
#pragma unroll
    for (int r = 0; r < AD_; r++) pos += ap[r] * aw[r][c];
    key_in[mrow * D_ + c] = val + pos;
  }
}

// ---------------- inside mask (conf folded in) ----------------
__global__ __launch_bounds__(256) void inside_kernel(const float* __restrict__ i2j_rm,
                                                     const float* __restrict__ conf_rm,
                                                     const float* __restrict__ mn,
                                                     const float* __restrict__ mx,
                                                     float* __restrict__ inside) {
  int row = blockIdx.x;  // i*900+a
  int i = row / A_;
  float mn0 = mn[row * 3 + 0], mn1 = mn[row * 3 + 1], mn2 = mn[row * 3 + 2];
  float mx0 = mx[row * 3 + 0], mx1 = mx[row * 3 + 1], mx2 = mx[row * 3 + 2];
#pragma unroll
  for (int it = 0; it < 5; it++) {
    int m = it * 256 + threadIdx.x;
    if (m < M_) {
      const float* cp = i2j_rm + ((long)i * M_ + m) * AD_;
      float c0 = cp[0], c1 = cp[1], c2 = cp[2];
      bool ins = (c0 >= mn0) && (c0 <= mx0) && (c1 >= mn1) && (c1 <= mx1) && (c2 >= mn2) && (c2 <= mx2);
      inside[(long)row * M_ + m] = ins ? conf_rm[(long)i * M_ + m] : 0.0f;
    }
  }
}

// ---------------- distance-bias precompute: Lbuf[i][m][a] = log1p(dist) ----------------
__global__ __launch_bounds__(256) void bias_kernel(const float* __restrict__ ban,
                                                   const float* __restrict__ i2j_rm,
                                                   float* __restrict__ Lbuf) {
  int i = blockIdx.x, m = blockIdx.y;
  const float* cp = i2j_rm + ((long)i * M_ + m) * AD_;
  float cx = cp[0], cy = cp[1];
  for (int a = threadIdx.x; a < A_; a += 256) {
    float dx = ban[(long)(i * A_ + a) * AD_ + 0] - cx;
    float dy = ban[(long)(i * A_ + a) * AD_ + 1] - cy;
    float dist = sqrtf(dx * dx + dy * dy + 1e-12f);
    Lbuf[((long)i * M_ + m) * A_ + a] = log1pf(dist);
  }
}

// ---------------- fp32 SIMT GEMM (kept for the tiny lam projection, N=8) ----------------
__global__ __launch_bounds__(256) void gemm_kernel(const float* __restrict__ A,
                                                   const float* __restrict__ B,
                                                   const float* __restrict__ bias,
                                                   const float* __restrict__ res,
                                                   float* __restrict__ C,
                                                   int Mr, int Nc, int Kc,
                                                   long sA, long sB, long sC) {
  int bz = blockIdx.z;
  A += (long)bz * sA;
  B += (long)bz * sB;
  C += (long)bz * sC;
  if (res) res += (long)bz * sC;
  __shared__ float As[16][65];
  __shared__ float Bs[16][65];
  int m0 = blockIdx.x * 64, n0 = blockIdx.y * 64;
  int tid = threadIdx.x;
  int tx = tid % 16, ty = tid / 16;
  float acc[4][4] = {};
  for (int k0 = 0; k0 < Kc; k0 += 16) {
#pragma unroll
    for (int r = 0; r < 4; r++) {
      int l = r * 256 + tid;
      int mm = l >> 4, kk = l & 15;
      int gm = m0 + mm, gk = k0 + kk;
      As[kk][mm] = (gm < Mr && gk < Kc) ? A[(long)gm * Kc + gk] : 0.0f;
    }
#pragma unroll
    for (int r = 0; r < 4; r++) {
      int l = r * 256 + tid;
      int nn = l & 63, kk = l >> 6;
      int gk = k0 + kk, gn = n0 + nn;
      Bs[kk][nn] = (gk < Kc && gn < Nc) ? B[(long)gk * Nc + gn] : 0.0f;
    }
    __syncthreads();
#pragma unroll
    for (int kk = 0; kk < 16; kk++) {
      float av[4], bv[4];
#pragma unroll
      for (int ii = 0; ii < 4; ii++) av[ii] = As[kk][ty * 4 + ii];
#pragma unroll
      for (int jjv = 0; jjv < 4; jjv++) bv[jjv] = Bs[kk][tx * 4 + jjv];
#pragma unroll
      for (int ii = 0; ii < 4; ii++)
#pragma unroll
        for (int jjv = 0; jjv < 4; jjv++) acc[ii][jjv] += av[ii] * bv[jjv];
    }
    __syncthreads();
  }
#pragma unroll
  for (int ii = 0; ii < 4; ii++) {
    int gm = m0 + ty * 4 + ii;
    if (gm >= Mr) continue;
#pragma unroll
    for (int jjv = 0; jjv < 4; jjv++) {
      int gn = n0 + tx * 4 + jjv;
      if (gn >= Nc) continue;
      float v = acc[ii][jjv];
      if (bias) v += bias[gn];
      if (res) v += res[(long)gm * Nc + gn];
      C[(long)gm * Nc + gn] = v;
    }
  }
}

// ---------------- MFMA fp16 GEMM: C = (A[+A2])@B (+bias) (+res), fp32 I/O ----------------
#define BM_ 64
#define BN_ 64
#define BK_ 32
#define LDK_ 40  // BK_+8 pad
__global__ __launch_bounds__(256) void gemm_mfma(const float* __restrict__ A,
                                                 const float* __restrict__ A2,
                                                 const float* __restrict__ B,
                                                 const float* __restrict__ bias,
                                                 const float* __restrict__ res,
                                                 float* __restrict__ C,
                                                 int Mr, int Nc, int Kc,
                                                 long sA, long sB, long sC) {
  int bz = blockIdx.z;
  A += (long)bz * sA;
  if (A2) A2 += (long)bz * sA;
  B += (long)bz * sB;
  C += (long)bz * sC;
  if (res) res += (long)bz * sC;
  __shared__ _Float16 As[BM_ * LDK_];
  __shared__ _Float16 Bt[BN_ * LDK_];
  int m0 = blockIdx.x * BM_, n0 = blockIdx.y * BN_;
  int tid = threadIdx.x;
  int wid = tid >> 6, lane = tid & 63;
  int wr = (wid >> 1) * 32, wc = (wid & 1) * 32;
  int lr = lane & 15;
  int lk = (lane >> 4) * 8;
  f32x4 acc[2][2] = {};
  for (int k0 = 0; k0 < Kc; k0 += BK_) {
    // stage A (64x32) -> As[m][k], fp16
#pragma unroll
    for (int r = 0; r < 8; r++) {
      int idx = r * 256 + tid;
      int mm = idx >> 5, kk = idx & 31;
      int gm = m0 + mm, gk = k0 + kk;
      float v = 0.0f;
      if (gm < Mr && gk < Kc) {
        v = A[(long)gm * Kc + gk];
        if (A2) v += A2[(long)gm * Kc + gk];
      }
      As[mm * LDK_ + kk] = (_Float16)v;
    }
    // stage B (32x64) transposed -> Bt[n][k], fp16
#pragma unroll
    for (int r = 0; r < 8; r++) {
      int idx = r * 256 + tid;
      int kk = idx >> 6, nn = idx & 63;
      int gk = k0 + kk, gn = n0 + nn;
      float v = (gk < Kc && gn < Nc) ? B[(long)gk * Nc + gn] : 0.0f;
      Bt[nn * LDK_ + kk] = (_Float16)v;
    }
    __syncthreads();
    f16x8 af[2], bf[2];
#pragma unroll
    for (int mi = 0; mi < 2; mi++) af[mi] = *(const f16x8*)&As[(wr + mi * 16 + lr) * LDK_ + lk];
#pragma unroll
    for (int ni = 0; ni < 2; ni++) bf[ni] = *(const f16x8*)&Bt[(wc + ni * 16 + lr) * LDK_ + lk];
#pragma unroll
    for (int mi = 0; mi < 2; mi++)
#pragma unroll
      for (int ni = 0; ni < 2; ni++)
        acc[mi][ni] = __builtin_amdgcn_mfma_f32_16x16x32_f16(af[mi], bf[ni], acc[mi][ni], 0, 0, 0);
    __syncthreads();
  }
#pragma unroll
  for (int mi = 0; mi < 2; mi++) {
#pragma unroll
    for (int ni = 0; ni < 2; ni++) {
#pragma unroll
      for (int rr = 0; rr < 4; rr++) {
        int row = m0 + wr + mi * 16 + (lane >> 4) * 4 + rr;
        int col = n0 + wc + ni * 16 + (lane & 15);
        if (row < Mr && col < Nc) {
          float v = acc[mi][ni][rr];
          if (bias) v += bias[col];
          if (res) v += res[(long)row * Nc + col];
          C[(long)row * Nc + col] = v;
        }
      }
    }
  }
}

// ---------------- flash attention: 32 queries x 8 m-groups per block ----------------
__global__ __launch_bounds__(256) void attn_kernel(const float* __restrict__ qh,
                                                   const float* __restrict__ kh,
                                                   const float* __restrict__ vh,
                                                   const float* __restrict__ lm_rm,
                                                   const float* __restrict__ Lbuf,
                                                   float* __restrict__ out) {
  int ih = blockIdx.y;
  int i = ih >> 3, h = ih & 7;
  int a0 = blockIdx.x * QT2_;
  int tid = threadIdx.x;
  int g = tid >> 5;   // m-group 0..7
  int qs = tid & 31;  // query slot
  int a = a0 + qs;
  int a_ld = (a < A_) ? a : A_ - 1;

  __shared__ float smem[8704];  // staging 7680 floats; merge overlay 8704 floats
  float* Ks = smem;             // [8][15][32]
  float* Vs = smem + NG_ * MC2_ * DH_;

  float q[DH_], o[DH_];
  const float* qp = qh + ((long)(i * A_ + a_ld)) * D_ + h * DH_;
#pragma unroll
  for (int d4 = 0; d4 < 8; d4++) {
    float4 t = *(const float4*)(qp + d4 * 4);
    q[d4 * 4 + 0] = t.x; q[d4 * 4 + 1] = t.y; q[d4 * 4 + 2] = t.z; q[d4 * 4 + 3] = t.w;
  }
  float lmv = lm_rm[(long)(i * A_ + a_ld) * H_ + h];
#pragma unroll
  for (int d = 0; d < DH_; d++) o[d] = 0.0f;
  float m_run = -INFINITY, s = 0.0f;

  const float* kb = kh + (long)i * M_ * D_ + h * DH_;
  const float* vb = vh + (long)i * M_ * D_ + h * DH_;
  const float* lbase = Lbuf + (long)i * M_ * A_ + a_ld;
  int mbase = g * GM_;
  float* Kg = Ks + g * (MC2_ * DH_);
  float* Vg = Vs + g * (MC2_ * DH_);

  for (int c = 0; c < NCH_; c++) {
    int m0 = mbase + c * MC2_;
    __syncthreads();
    for (int idx = qs; idx < MC2_ * 8; idx += 32) {
      int row = idx >> 3, d4 = idx & 7;
      *(float4*)&Kg[row * DH_ + d4 * 4] = *(const float4*)(kb + (long)(m0 + row) * D_ + d4 * 4);
      *(float4*)&Vg[row * DH_ + d4 * 4] = *(const float4*)(vb + (long)(m0 + row) * D_ + d4 * 4);
    }
    __syncthreads();
    float lg[MC2_];
    float cmax = -INFINITY;
#pragma unroll
    for (int mm = 0; mm < MC2_; mm++) {
      float dot = 0.0f;
#pragma unroll
      for (int d = 0; d < DH_; d++) dot += q[d] * Kg[mm * DH_ + d];
      float L = lbase[(long)(m0 + mm) * A_];
      lg[mm] = dot * 0.17677669529663687f - L * lmv;
      cmax = fmaxf(cmax, lg[mm]);
    }
    float nm = fmaxf(m_run, cmax);
    float corr = __expf(m_run - nm);
    s *= corr;
#pragma unroll
    for (int d = 0; d < DH_; d++) o[d] *= corr;
    m_run = nm;
#pragma unroll
    for (int mm = 0; mm < MC2_; mm++) {
      float p = __expf(lg[mm] - m_run);
      s += p;
#pragma unroll
      for (int d = 0; d < DH_; d++) o[d] += p * Vg[mm * DH_ + d];
    }
  }

  // write partials to LDS (overlay) and merge with all 256 threads
  __syncthreads();
  float* mbuf = smem;  // [8][32][34]
  float* mb = mbuf + ((g * 32 + qs) * 34);
  mb[0] = m_run;
  mb[1] = s;
#pragma unroll
  for (int d = 0; d < DH_; d++) mb[2 + d] = o[d];
  __syncthreads();
  // thread t: q2 = t>>3, handles d = (t&7)*4 .. +3
  int q2 = tid >> 3, dgq = tid & 7;
  if (a0 + q2 < A_) {
    float mstar = -INFINITY;
#pragma unroll
    for (int gg = 0; gg < 8; gg++) mstar = fmaxf(mstar, mbuf[(gg * 32 + q2) * 34]);
    float e[8];
    float den = 0.0f;
#pragma unroll
    for (int gg = 0; gg < 8; gg++) {
      e[gg] = __expf(mbuf[(gg * 32 + q2) * 34] - mstar);
      den += e[gg] * mbuf[(gg * 32 + q2) * 34 + 1];
    }
    float invd = 1.0f / den;
    float* op = out + ((long)(i * A_ + a0 + q2)) * D_ + h * DH_ + dgq * 4;
#pragma unroll
    for (int dd = 0; dd < 4; dd++) {
      float num = 0.0f;
#pragma unroll
      for (int gg = 0; gg < 8; gg++) num += e[gg] * mbuf[(gg * 32 + q2) * 34 + 2 + dgq * 4 + dd];
      op[dd] = num * invd;
    }
  }
}

// ---------------- LayerNorm ----------------
__global__ __launch_bounds__(256) void ln_kernel(const float* __restrict__ x,
                                                 const float* __restrict__ g,
                                                 const float* __restrict__ b,
                                                 float* __restrict__ out) {
  int row = blockIdx.x;
  int t = threadIdx.x;
  float v = x[(long)row * D_ + t];
  float s = v, sq = v * v;
#pragma unroll
  for (int o = 32; o; o >>= 1) {
    s += __shfl_xor(s, o, 64);
    sq += __shfl_xor(sq, o, 64);
  }
  __shared__ float ss[4], ssq[4];
  int wid = t >> 6, lane = t & 63;
  if (lane == 0) { ss[wid] = s; ssq[wid] = sq; }
  __syncthreads();
  float ts = ss[0] + ss[1] + ss[2] + ss[3];
  float tq = ssq[0] + ssq[1] + ssq[2] + ssq[3];
  float mean = ts / (float)D_;
  float var = tq / (float)D_ - mean * mean;
  out[(long)row * D_ + t] = (v - mean) * rsqrtf(var + 1e-5f) * g[t] + b[t];
}

extern "C" void kernel_launch(void* const* d_in, const int* in_sizes, int n_in,
                              void* d_out, int out_size, void* d_ws, size_t ws_size,
                              hipStream_t stream) {
  const float* i2j_anchor   = (const float*)d_in[0];
  const float* b_anchor     = (const float*)d_in[1];
  const float* b_feature    = (const float*)d_in[2];
  const float* tm           = (const float*)d_in[3];
  const float* anchor_embed = (const float*)d_in[4];
  const float* w_roi  = (const float*)d_in[5];
  const float* b_roi  = (const float*)d_in[6];
  const float* bn_g   = (const float*)d_in[7];
  const float* bn_b   = (const float*)d_in[8];
  const float* fc1_w  = (const float*)d_in[9];
  const float* fc1_b  = (const float*)d_in[10];
  const float* fc2_w  = (const float*)d_in[11];
  const float* fc2_b  = (const float*)d_in[12];
  const float* anc_w  = (const float*)d_in[13];
  const float* anc_b  = (const float*)d_in[14];
  const float* lam_w  = (const float*)d_in[15];
  const float* lam_b  = (const float*)d_in[16];
  const float* wq = (const float*)d_in[17];
  const float* bq = (const float*)d_in[18];
  const float* wk = (const float*)d_in[19];
  const float* bk = (const float*)d_in[20];
  const float* wv = (const float*)d_in[21];
  const float* bv = (const float*)d_in[22];
  const float* wo = (const float*)d_in[23];
  const float* bo = (const float*)d_in[24];
  const float* ln_g = (const float*)d_in[25];
  const float* ln_b = (const float*)d_in[26];

  float* ws = (float*)d_ws;
  size_t off = 0;
  auto alloc = [&](size_t n) { float* p = ws + off; off += n; return p; };

  float* scores    = alloc(N_ * A_);
  int*   top_idx   = (int*)alloc(N_ * K_);
  float* conf      = alloc(N_ * K_);
  float* t_mlp     = alloc(20 * D_);
  float* bmn       = alloc(N_ * A_ * 3);
  float* bmx       = alloc(N_ * A_ * 3);
  float* key_feat  = alloc((size_t)N_ * M_ * D_);
  float* conf_rm   = alloc((size_t)N_ * M_);
  float* i2j_rm    = alloc((size_t)N_ * M_ * AD_);
  float* key_in    = alloc((size_t)N_ * M_ * D_);
  float* inside    = alloc((size_t)N_ * A_ * M_);   // reused as Lbuf [i][m][a]
  float* bf_upd    = alloc((size_t)N_ * A_ * D_);
  float* qhb       = alloc((size_t)N_ * A_ * D_);
  float* kh_rm     = alloc((size_t)N_ * M_ * D_);
  float* vh_rm     = alloc((size_t)N_ * M_ * D_);
  float* lm_rm     = alloc((size_t)N_ * A_ * H_);
  float* att_out   = alloc((size_t)N_ * A_ * D_);
  float* res_buf   = alloc((size_t)N_ * A_ * D_);
  float* Lbuf      = inside;  // alias: inside dead after agg GEMM

  // 1. scores
  score_kernel<<<(N_ * A_ + 3) / 4, 256, 0, stream>>>(b_feature, w_roi, b_roi, scores);
  // 2. top-k
  topk_kernel<<<N_, 1024, 0, stream>>>(scores, top_idx, conf);
  // 3. tiny MLP (20 blocks)
  mlp_kernel<<<20, 256, 0, stream>>>(tm, bn_g, bn_b, fc1_w, fc1_b, fc2_w, fc2_b, t_mlp);
  // 4. bbox
  bbox_kernel<<<(N_ * A_ + 255) / 256, 256, 0, stream>>>(b_anchor, bmn, bmx);
  // 5. gather (k-parallel: 20 x 5 blocks)
  gather_kernel<<<dim3(N_ * NM1_, K_ / GKT_), 256, 0, stream>>>(b_feature, i2j_anchor, top_idx, conf,
                                                                anc_w, anc_b, t_mlp,
                                                                key_feat, conf_rm, i2j_rm, key_in);
  // 6. inside mask
  inside_kernel<<<N_ * A_, 256, 0, stream>>>(i2j_rm, conf_rm, bmn, bmx, inside);
  // 7. agg GEMM (MFMA): bf_upd = inside @ key_feat + b_feature
  gemm_mfma<<<dim3(15, 4, N_), 256, 0, stream>>>(inside, nullptr, key_feat, nullptr, b_feature, bf_upd,
                                                 A_, D_, M_,
                                                 (long)A_ * M_, (long)M_ * D_, (long)A_ * D_);
  // 8. bias precompute (reuses inside's memory)
  bias_kernel<<<dim3(N_, M_), 256, 0, stream>>>(b_anchor, i2j_rm, Lbuf);
  // 9. lm = bf_upd @ lam_w + lam_b (fp32, tiny N)
  gemm_kernel<<<dim3(71, 1, 1), 256, 0, stream>>>(bf_upd, lam_w, lam_b, nullptr, lm_rm,
                                                  N_ * A_, H_, D_, 0, 0, 0);
  // 10. qh = (bf_upd + anchor_embed) @ wq + bq   (fused add)
  gemm_mfma<<<dim3(71, 4, 1), 256, 0, stream>>>(bf_upd, anchor_embed, wq, bq, nullptr, qhb,
                                                N_ * A_, D_, D_, 0, 0, 0);
  // 11. kh = key_in @ wk + bk
  gemm_mfma<<<dim3(94, 4, 1), 256, 0, stream>>>(key_in, nullptr, wk, bk, nullptr, kh_rm,
                                                N_ * M_, D_, D_, 0, 0, 0);
  // 12. vh = key_feat @ wv + bv
  gemm_mfma<<<dim3(94, 4, 1), 256, 0, stream>>>(key_feat, nullptr, wv, bv, nullptr, vh_rm,
                                                N_ * M_, D_, D_, 0, 0, 0);
  // 13. flash attention (a-tile fastest for K/V L2 reuse)
  attn_kernel<<<dim3((A_ + QT2_ - 1) / QT2_, N_ * H_), 256, 0, stream>>>(qhb, kh_rm, vh_rm,
                                                                         lm_rm, Lbuf, att_out);
  // 14. out projection + residual
  gemm_mfma<<<dim3(71, 4, 1), 256, 0, stream>>>(att_out, nullptr, wo, bo, bf_upd, res_buf,
                                                N_ * A_, D_, D_, 0, 0, 0);
  // 15. LayerNorm -> d_out
  ln_kernel<<<N_ * A_, 256, 0, stream>>>(res_buf, ln_g, ln_b, (float*)d_out);
}

// Round 4
// 785.634 us; speedup vs baseline: 1.5802x; 1.5802x over previous
//
#include <hip/hip_runtime.h>
#include <math.h>

#define N_ 5
#define A_ 900
#define AD_ 8
#define D_ 256
#define H_ 8
#define DH_ 32
#define K_ 300
#define NM1_ 4
#define M_ 1200  // K_*(N_-1)

// attention tiling: 8 m-groups x 64 queries, 150 keys/group in 15-row chunks
#define QT_ 64
#define NG_ 8
#define GK_ 150
#define MC_ 15
#define NCH_ 10
#define KROW_ 36  // 32 K floats + cx + cy + 2 pad

typedef _Float16 f16x8 __attribute__((ext_vector_type(8)));
typedef float f32x4 __attribute__((ext_vector_type(4)));

// ---------------- scores: sigmoid(b_feature @ w_roi + b_roi) ----------------
__global__ __launch_bounds__(256) void score_kernel(const float* __restrict__ bf,
                                                    const float* __restrict__ w,
                                                    const float* __restrict__ b,
                                                    float* __restrict__ scores) {
  int wid = threadIdx.x >> 6, lane = threadIdx.x & 63;
  int row = blockIdx.x * 4 + wid;
  if (row >= N_ * A_) return;
  const float* x = bf + (long)row * D_;
  float dot = 0.f;
#pragma unroll
  for (int t = 0; t < 4; t++) dot += x[lane + 64 * t] * w[lane + 64 * t];
#pragma unroll
  for (int o = 32; o; o >>= 1) dot += __shfl_xor(dot, o, 64);
  if (lane == 0) scores[row] = 1.0f / (1.0f + expf(-(dot + b[0])));
}

// ---------------- top-k via bitonic sort (1 block per batch row) ----------------
__global__ __launch_bounds__(1024) void topk_kernel(const float* __restrict__ scores,
                                                    int* __restrict__ top_idx,
                                                    float* __restrict__ conf) {
  __shared__ float sc[1024];
  __shared__ int si[1024];
  int i = blockIdx.x, t = threadIdx.x;
  sc[t] = (t < A_) ? scores[i * A_ + t] : -INFINITY;
  si[t] = t;
  __syncthreads();
  for (int k = 2; k <= 1024; k <<= 1) {
    for (int j = k >> 1; j > 0; j >>= 1) {
      int ixj = t ^ j;
      if (ixj > t) {
        bool dir = ((t & k) == 0);
        float a = sc[t], b = sc[ixj];
        bool sw = dir ? (a < b) : (a > b);
        if (sw) {
          sc[t] = b; sc[ixj] = a;
          int tmp = si[t]; si[t] = si[ixj]; si[ixj] = tmp;
        }
      }
      __syncthreads();
    }
  }
  if (t < K_) {
    top_idx[i * K_ + t] = si[t];
    conf[i * K_ + t] = sc[t] > 0.5f ? 1.0f : 0.0f;
  }
}

// ---------------- tiny MLP: one block per transform row ----------------
__global__ __launch_bounds__(256) void mlp_kernel(const float* __restrict__ tm,
                                                  const float* __restrict__ bn_g, const float* __restrict__ bn_b,
                                                  const float* __restrict__ fc1_w, const float* __restrict__ fc1_b,
                                                  const float* __restrict__ fc2_w, const float* __restrict__ fc2_b,
                                                  float* __restrict__ t_out) {
  int r = blockIdx.x;  // 0..19
  int t = threadIdx.x;
  __shared__ float x[20][12];
  __shared__ float y[12];
  __shared__ float hbuf[D_];
  if (t < 240) {
    int rr = t / 12, f = t % 12;
    int i = rr / NM1_, jj = rr % NM1_;
    int j = jj < i ? jj : jj + 1;
    int r4 = f / 4, c4 = f % 4;
    x[rr][f] = tm[((long)(i * N_ + j) * 4 + r4) * 4 + c4];
  }
  __syncthreads();
  if (t < 12) {
    float s = 0.f;
    for (int rr = 0; rr < 20; rr++) s += x[rr][t];
    float m = s / 20.0f;
    float v = 0.f;
    for (int rr = 0; rr < 20; rr++) { float d = x[rr][t] - m; v += d * d; }
    v /= 20.0f;
    y[t] = (x[r][t] - m) * rsqrtf(v + 1e-5f) * bn_g[t] + bn_b[t];
  }
  __syncthreads();
  float acc = fc1_b[t];
#pragma unroll
  for (int f = 0; f < 12; f++) acc += y[f] * fc1_w[f * D_ + t];
  hbuf[t] = fmaxf(acc, 0.0f);
  __syncthreads();
  float acc2 = fc2_b[t];
  for (int k = 0; k < D_; k++) acc2 += hbuf[k] * fc2_w[k * D_ + t];
  t_out[r * D_ + t] = acc2;
}

// ---------------- gather: key_feat, i2j_rm, conf_rm, key_in (k-parallel) ----------------
#define GKT_ 30  // k per block
__global__ __launch_bounds__(256) void gather_kernel(const float* __restrict__ b_feature,
                                                     const float* __restrict__ i2j_anchor,
                                                     const int* __restrict__ top_idx,
                                                     const float* __restrict__ conf,
                                                     const float* __restrict__ anc_w,
                                                     const float* __restrict__ anc_b,
                                                     const float* __restrict__ t_mlp,
                                                     float* __restrict__ key_feat,
                                                     float* __restrict__ conf_rm,
                                                     float* __restrict__ i2j_rm,
                                                     float* __restrict__ key_in) {
  int blk = blockIdx.x;  // i*4+jj
  int i = blk / NM1_, jj = blk % NM1_;
  int j = jj < i ? jj : jj + 1;
  int k0 = blockIdx.y * GKT_;
  int c = threadIdx.x;
  __shared__ float aw[AD_][D_];
#pragma unroll
  for (int r = 0; r < AD_; r++) aw[r][c] = anc_w[r * D_ + c];
  float ab = anc_b[c];
  float tv = t_mlp[(i * NM1_ + jj) * D_ + c];
  __syncthreads();
  for (int k = k0; k < k0 + GKT_; k++) {
    int idx = top_idx[j * K_ + k];
    float cf = conf[j * K_ + k];
    const float* src = b_feature + ((long)(j * A_ + idx)) * D_;
    float val = src[c];
    long mrow = (long)i * M_ + jj * K_ + k;
    key_feat[mrow * D_ + c] = val;
    const float* ap = i2j_anchor + ((long)((i * N_ + j) * A_ + idx)) * AD_;
    if (c < AD_) i2j_rm[mrow * AD_ + c] = ap[c];
    if (c == 0) conf_rm[mrow] = cf;
    float pos = ab + tv;
#pragma unroll
    for (int r = 0; r < AD_; r++) pos += ap[r] * aw[r][c];
    key_in[mrow * D_ + c] = val + pos;
  }
}

// ---------------- inside mask (bbox computed inline, conf folded in) ----------------
__global__ __launch_bounds__(256) void inside_kernel(const float* __restrict__ i2j_rm,
                                                     const float* __restrict__ conf_rm,
                                                     const float* __restrict__ ban,
                                                     float* __restrict__ inside) {
  int row = blockIdx.x;  // i*900+a
  int i = row / A_;
  const float* ap = ban + (long)row * AD_;
  float x = ap[0], y = ap[1], z = ap[2];
  float w = expf(ap[3]), l = expf(ap[4]), hh = expf(ap[5]);
  float yaw = atan2f(ap[6], ap[7]);
  float ca = fabsf(cosf(yaw)), sa = fabsf(sinf(yaw));
  float ex = 0.5f * (l * ca + w * sa);
  float ey = 0.5f * (l * sa + w * ca);
  float ez = 0.5f * hh;
  float mn0 = x - ex, mn1 = y - ey, mn2 = z - ez;
  float mx0 = x + ex, mx1 = y + ey, mx2 = z + ez;
#pragma unroll
  for (int it = 0; it < 5; it++) {
    int m = it * 256 + threadIdx.x;
    if (m < M_) {
      const float* cp = i2j_rm + ((long)i * M_ + m) * AD_;
      float c0 = cp[0], c1 = cp[1], c2 = cp[2];
      bool ins = (c0 >= mn0) && (c0 <= mx0) && (c1 >= mn1) && (c1 <= mx1) && (c2 >= mn2) && (c2 <= mx2);
      inside[(long)row * M_ + m] = ins ? conf_rm[(long)i * M_ + m] : 0.0f;
    }
  }
}

// ---------------- fp32 SIMT GEMM (kept for the tiny lam projection, N=8) ----------------
__global__ __launch_bounds__(256) void gemm_kernel(const float* __restrict__ A,
                                                   const float* __restrict__ B,
                                                   const float* __restrict__ bias,
                                                   const float* __restrict__ res,
                                                   float* __restrict__ C,
                                                   int Mr, int Nc, int Kc,
                                                   long sA, long sB, long sC) {
  int bz = blockIdx.z;
  A += (long)bz * sA;
  B += (long)bz * sB;
  C += (long)bz * sC;
  if (res) res += (long)bz * sC;
  __shared__ float As[16][65];
  __shared__ float Bs[16][65];
  int m0 = blockIdx.x * 64, n0 = blockIdx.y * 64;
  int tid = threadIdx.x;
  int tx = tid % 16, ty = tid / 16;
  float acc[4][4] = {};
  for (int k0 = 0; k0 < Kc; k0 += 16) {
#pragma unroll
    for (int r = 0; r < 4; r++) {
      int l = r * 256 + tid;
      int mm = l >> 4, kk = l & 15;
      int gm = m0 + mm, gk = k0 + kk;
      As[kk][mm] = (gm < Mr && gk < Kc) ? A[(long)gm * Kc + gk] : 0.0f;
    }
#pragma unroll
    for (int r = 0; r < 4; r++) {
      int l = r * 256 + tid;
      int nn = l & 63, kk = l >> 6;
      int gk = k0 + kk, gn = n0 + nn;
      Bs[kk][nn] = (gk < Kc && gn < Nc) ? B[(long)gk * Nc + gn] : 0.0f;
    }
    __syncthreads();
#pragma unroll
    for (int kk = 0; kk < 16; kk++) {
      float av[4], bv[4];
#pragma unroll
      for (int ii = 0; ii < 4; ii++) av[ii] = As[kk][ty * 4 + ii];
#pragma unroll
      for (int jjv = 0; jjv < 4; jjv++) bv[jjv] = Bs[kk][tx * 4 + jjv];
#pragma unroll
      for (int ii = 0; ii < 4; ii++)
#pragma unroll
        for (int jjv = 0; jjv < 4; jjv++) acc[ii][jjv] += av[ii] * bv[jjv];
    }
    __syncthreads();
  }
#pragma unroll
  for (int ii = 0; ii < 4; ii++) {
    int gm = m0 + ty * 4 + ii;
    if (gm >= Mr) continue;
#pragma unroll
    for (int jjv = 0; jjv < 4; jjv++) {
      int gn = n0 + tx * 4 + jjv;
      if (gn >= Nc) continue;
      float v = acc[ii][jjv];
      if (bias) v += bias[gn];
      if (res) v += res[(long)gm * Nc + gn];
      C[(long)gm * Nc + gn] = v;
    }
  }
}

// ---------------- MFMA fp16 GEMM: C = (A[+A2])@B (+bias) (+res), fp32 I/O ----------------
#define BM_ 64
#define BN_ 64
#define BK_ 32
#define LDK_ 40  // BK_+8 pad
__global__ __launch_bounds__(256) void gemm_mfma(const float* __restrict__ A,
                                                 const float* __restrict__ A2,
                                                 const float* __restrict__ B,
                                                 const float* __restrict__ bias,
                                                 const float* __restrict__ res,
                                                 float* __restrict__ C,
                                                 int Mr, int Nc, int Kc,
                                                 long sA, long sB, long sC) {
  int bz = blockIdx.z;
  A += (long)bz * sA;
  if (A2) A2 += (long)bz * sA;
  B += (long)bz * sB;
  C += (long)bz * sC;
  if (res) res += (long)bz * sC;
  __shared__ _Float16 As[BM_ * LDK_];
  __shared__ _Float16 Bt[BN_ * LDK_];
  int m0 = blockIdx.x * BM_, n0 = blockIdx.y * BN_;
  int tid = threadIdx.x;
  int wid = tid >> 6, lane = tid & 63;
  int wr = (wid >> 1) * 32, wc = (wid & 1) * 32;
  int lr = lane & 15;
  int lk = (lane >> 4) * 8;
  f32x4 acc[2][2] = {};
  for (int k0 = 0; k0 < Kc; k0 += BK_) {
#pragma unroll
    for (int r = 0; r < 8; r++) {
      int idx = r * 256 + tid;
      int mm = idx >> 5, kk = idx & 31;
      int gm = m0 + mm, gk = k0 + kk;
      float v = 0.0f;
      if (gm < Mr && gk < Kc) {
        v = A[(long)gm * Kc + gk];
        if (A2) v += A2[(long)gm * Kc + gk];
      }
      As[mm * LDK_ + kk] = (_Float16)v;
    }
#pragma unroll
    for (int r = 0; r < 8; r++) {
      int idx = r * 256 + tid;
      int kk = idx >> 6, nn = idx & 63;
      int gk = k0 + kk, gn = n0 + nn;
      float v = (gk < Kc && gn < Nc) ? B[(long)gk * Nc + gn] : 0.0f;
      Bt[nn * LDK_ + kk] = (_Float16)v;
    }
    __syncthreads();
    f16x8 af[2], bf[2];
#pragma unroll
    for (int mi = 0; mi < 2; mi++) af[mi] = *(const f16x8*)&As[(wr + mi * 16 + lr) * LDK_ + lk];
#pragma unroll
    for (int ni = 0; ni < 2; ni++) bf[ni] = *(const f16x8*)&Bt[(wc + ni * 16 + lr) * LDK_ + lk];
#pragma unroll
    for (int mi = 0; mi < 2; mi++)
#pragma unroll
      for (int ni = 0; ni < 2; ni++)
        acc[mi][ni] = __builtin_amdgcn_mfma_f32_16x16x32_f16(af[mi], bf[ni], acc[mi][ni], 0, 0, 0);
    __syncthreads();
  }
#pragma unroll
  for (int mi = 0; mi < 2; mi++) {
#pragma unroll
    for (int ni = 0; ni < 2; ni++) {
#pragma unroll
      for (int rr = 0; rr < 4; rr++) {
        int row = m0 + wr + mi * 16 + (lane >> 4) * 4 + rr;
        int col = n0 + wc + ni * 16 + (lane & 15);
        if (row < Mr && col < Nc) {
          float v = acc[mi][ni][rr];
          if (bias) v += bias[col];
          if (res) v += res[(long)row * Nc + col];
          C[(long)row * Nc + col] = v;
        }
      }
    }
  }
}

// ---------------- flash attention: bias on-the-fly, 8 m-groups x 64 queries ----------------
__global__ __launch_bounds__(512) void attn_kernel(const float* __restrict__ qh,
                                                   const float* __restrict__ kh,
                                                   const float* __restrict__ vh,
                                                   const float* __restrict__ lm_rm,
                                                   const float* __restrict__ ban,
                                                   const float* __restrict__ i2j_rm,
                                                   float* __restrict__ out) {
  int ih = blockIdx.y;
  int i = ih >> 3, h = ih & 7;
  int a0 = blockIdx.x * QT_;
  int tid = threadIdx.x;
  int g = tid >> 6;   // m-group 0..7
  int qs = tid & 63;  // query slot
  int a = a0 + qs;
  int a_ld = (a < A_) ? a : A_ - 1;

  __shared__ float smem[8704];  // staging 8160 floats; merge overlay [4][64][34]=8704
  float* Ks = smem;                       // [8][15][36]
  float* Vs = smem + NG_ * MC_ * KROW_;   // [8][15][32]

  float q[DH_], o[DH_];
  const float* qp = qh + ((long)(i * A_ + a_ld)) * D_ + h * DH_;
#pragma unroll
  for (int d4 = 0; d4 < 8; d4++) {
    float4 t = *(const float4*)(qp + d4 * 4);
    q[d4 * 4 + 0] = t.x; q[d4 * 4 + 1] = t.y; q[d4 * 4 + 2] = t.z; q[d4 * 4 + 3] = t.w;
  }
  float lmv = lm_rm[(long)(i * A_ + a_ld) * H_ + h];
  float ax = ban[(long)(i * A_ + a_ld) * AD_ + 0];
  float ay = ban[(long)(i * A_ + a_ld) * AD_ + 1];
#pragma unroll
  for (int d = 0; d < DH_; d++) o[d] = 0.0f;
  float m_run = -INFINITY, s = 0.0f;

  const float* kb = kh + (long)i * M_ * D_ + h * DH_;
  const float* vb = vh + (long)i * M_ * D_ + h * DH_;
  const float* ib = i2j_rm + (long)i * M_ * AD_;
  int mbase = g * GK_;
  float* Kg = Ks + g * (MC_ * KROW_);
  float* Vg = Vs + g * (MC_ * DH_);

  for (int c = 0; c < NCH_; c++) {
    int m0 = mbase + c * MC_;
    __syncthreads();
    for (int idx = qs; idx < MC_ * 8; idx += 64) {
      int row = idx >> 3, d4 = idx & 7;
      *(float4*)&Kg[row * KROW_ + d4 * 4] = *(const float4*)(kb + (long)(m0 + row) * D_ + d4 * 4);
      *(float4*)&Vg[row * DH_ + d4 * 4] = *(const float4*)(vb + (long)(m0 + row) * D_ + d4 * 4);
    }
    if (qs < MC_) {
      Kg[qs * KROW_ + 32] = ib[(long)(m0 + qs) * AD_ + 0];
      Kg[qs * KROW_ + 33] = ib[(long)(m0 + qs) * AD_ + 1];
    }
    __syncthreads();
    float lg[MC_];
    float cmax = -INFINITY;
#pragma unroll
    for (int mm = 0; mm < MC_; mm++) {
      float dot = 0.0f;
#pragma unroll
      for (int d = 0; d < DH_; d++) dot += q[d] * Kg[mm * KROW_ + d];
      float dx = ax - Kg[mm * KROW_ + 32];
      float dy = ay - Kg[mm * KROW_ + 33];
      float L = log1pf(sqrtf(dx * dx + dy * dy + 1e-12f));
      lg[mm] = dot * 0.17677669529663687f - L * lmv;
      cmax = fmaxf(cmax, lg[mm]);
    }
    float nm = fmaxf(m_run, cmax);
    float corr = __expf(m_run - nm);
    s *= corr;
#pragma unroll
    for (int d = 0; d < DH_; d++) o[d] *= corr;
    m_run = nm;
#pragma unroll
    for (int mm = 0; mm < MC_; mm++) {
      float p = __expf(lg[mm] - m_run);
      s += p;
#pragma unroll
      for (int d = 0; d < DH_; d++) o[d] += p * Vg[mm * DH_ + d];
    }
  }

  // merge 8 -> 4 -> 1 via LDS overlay
  __syncthreads();
  float* mbuf = smem;  // [4][64][34]
  if (g >= 4) {
    float* mb = &mbuf[((g - 4) * 64 + qs) * 34];
    mb[0] = m_run; mb[1] = s;
#pragma unroll
    for (int d = 0; d < DH_; d++) mb[2 + d] = o[d];
  }
  __syncthreads();
  if (g < 4) {
    float* mb = &mbuf[(g * 64 + qs) * 34];
    float m1 = mb[0], s1 = mb[1];
    float nm = fmaxf(m_run, m1);
    float e0 = __expf(m_run - nm), e1 = __expf(m1 - nm);
    s = s * e0 + s1 * e1;
#pragma unroll
    for (int d = 0; d < DH_; d++) o[d] = o[d] * e0 + mb[2 + d] * e1;
    m_run = nm;
  }
  __syncthreads();
  if (g >= 1 && g < 4) {
    float* mb = &mbuf[((g - 1) * 64 + qs) * 34];
    mb[0] = m_run; mb[1] = s;
#pragma unroll
    for (int d = 0; d < DH_; d++) mb[2 + d] = o[d];
  }
  __syncthreads();
  if (g == 0) {
#pragma unroll
    for (int gg = 0; gg < 3; gg++) {
      float* mb = &mbuf[(gg * 64 + qs) * 34];
      float m1 = mb[0], s1 = mb[1];
      float nm = fmaxf(m_run, m1);
      float e0 = __expf(m_run - nm), e1 = __expf(m1 - nm);
      s = s * e0 + s1 * e1;
#pragma unroll
      for (int d = 0; d < DH_; d++) o[d] = o[d] * e0 + mb[2 + d] * e1;
      m_run = nm;
    }
    if (a < A_) {
      float inv = 1.0f / s;
      float* op = out + ((long)(i * A_ + a)) * D_ + h * DH_;
#pragma unroll
      for (int d4 = 0; d4 < 8; d4++) {
        float4 t;
        t.x = o[d4 * 4 + 0] * inv; t.y = o[d4 * 4 + 1] * inv;
        t.z = o[d4 * 4 + 2] * inv; t.w = o[d4 * 4 + 3] * inv;
        *(float4*)(op + d4 * 4) = t;
      }
    }
  }
}

// ---------------- LayerNorm ----------------
__global__ __launch_bounds__(256) void ln_kernel(const float* __restrict__ x,
                                                 const float* __restrict__ g,
                                                 const float* __restrict__ b,
                                                 float* __restrict__ out) {
  int row = blockIdx.x;
  int t = threadIdx.x;
  float v = x[(long)row * D_ + t];
  float s = v, sq = v * v;
#pragma unroll
  for (int o = 32; o; o >>= 1) {
    s += __shfl_xor(s, o, 64);
    sq += __shfl_xor(sq, o, 64);
  }
  __shared__ float ss[4], ssq[4];
  int wid = t >> 6, lane = t & 63;
  if (lane == 0) { ss[wid] = s; ssq[wid] = sq; }
  __syncthreads();
  float ts = ss[0] + ss[1] + ss[2] + ss[3];
  float tq = ssq[0] + ssq[1] + ssq[2] + ssq[3];
  float mean = ts / (float)D_;
  float var = tq / (float)D_ - mean * mean;
  out[(long)row * D_ + t] = (v - mean) * rsqrtf(var + 1e-5f) * g[t] + b[t];
}

extern "C" void kernel_launch(void* const* d_in, const int* in_sizes, int n_in,
                              void* d_out, int out_size, void* d_ws, size_t ws_size,
                              hipStream_t stream) {
  const float* i2j_anchor   = (const float*)d_in[0];
  const float* b_anchor     = (const float*)d_in[1];
  const float* b_feature    = (const float*)d_in[2];
  const float* tm           = (const float*)d_in[3];
  const float* anchor_embed = (const float*)d_in[4];
  const float* w_roi  = (const float*)d_in[5];
  const float* b_roi  = (const float*)d_in[6];
  const float* bn_g   = (const float*)d_in[7];
  const float* bn_b   = (const float*)d_in[8];
  const float* fc1_w  = (const float*)d_in[9];
  const float* fc1_b  = (const float*)d_in[10];
  const float* fc2_w  = (const float*)d_in[11];
  const float* fc2_b  = (const float*)d_in[12];
  const float* anc_w  = (const float*)d_in[13];
  const float* anc_b  = (const float*)d_in[14];
  const float* lam_w  = (const float*)d_in[15];
  const float* lam_b  = (const float*)d_in[16];
  const float* wq = (const float*)d_in[17];
  const float* bq = (const float*)d_in[18];
  const float* wk = (const float*)d_in[19];
  const float* bk = (const float*)d_in[20];
  const float* wv = (const float*)d_in[21];
  const float* bv = (const float*)d_in[22];
  const float* wo = (const float*)d_in[23];
  const float* bo = (const float*)d_in[24];
  const float* ln_g = (const float*)d_in[25];
  const float* ln_b = (const float*)d_in[26];

  float* ws = (float*)d_ws;
  size_t off = 0;
  auto alloc = [&](size_t n) { float* p = ws + off; off += n; return p; };

  float* scores    = alloc(N_ * A_);
  int*   top_idx   = (int*)alloc(N_ * K_);
  float* conf      = alloc(N_ * K_);
  float* t_mlp     = alloc(20 * D_);
  float* key_feat  = alloc((size_t)N_ * M_ * D_);
  float* conf_rm   = alloc((size_t)N_ * M_);
  float* i2j_rm    = alloc((size_t)N_ * M_ * AD_);
  float* key_in    = alloc((size_t)N_ * M_ * D_);
  float* inside    = alloc((size_t)N_ * A_ * M_);
  float* bf_upd    = alloc((size_t)N_ * A_ * D_);
  float* qhb       = alloc((size_t)N_ * A_ * D_);
  float* kh_rm     = alloc((size_t)N_ * M_ * D_);
  float* vh_rm     = alloc((size_t)N_ * M_ * D_);
  float* lm_rm     = alloc((size_t)N_ * A_ * H_);
  float* att_out   = alloc((size_t)N_ * A_ * D_);
  float* res_buf   = alloc((size_t)N_ * A_ * D_);

  // 1. scores
  score_kernel<<<(N_ * A_ + 3) / 4, 256, 0, stream>>>(b_feature, w_roi, b_roi, scores);
  // 2. top-k
  topk_kernel<<<N_, 1024, 0, stream>>>(scores, top_idx, conf);
  // 3. tiny MLP (20 blocks)
  mlp_kernel<<<20, 256, 0, stream>>>(tm, bn_g, bn_b, fc1_w, fc1_b, fc2_w, fc2_b, t_mlp);
  // 4. gather (k-parallel: 20 x 10 blocks)
  gather_kernel<<<dim3(N_ * NM1_, K_ / GKT_), 256, 0, stream>>>(b_feature, i2j_anchor, top_idx, conf,
                                                                anc_w, anc_b, t_mlp,
                                                                key_feat, conf_rm, i2j_rm, key_in);
  // 5. inside mask (bbox inline)
  inside_kernel<<<N_ * A_, 256, 0, stream>>>(i2j_rm, conf_rm, b_anchor, inside);
  // 6. agg GEMM (MFMA): bf_upd = inside @ key_feat + b_feature
  gemm_mfma<<<dim3(15, 4, N_), 256, 0, stream>>>(inside, nullptr, key_feat, nullptr, b_feature, bf_upd,
                                                 A_, D_, M_,
                                                 (long)A_ * M_, (long)M_ * D_, (long)A_ * D_);
  // 7. lm = bf_upd @ lam_w + lam_b (fp32, tiny N)
  gemm_kernel<<<dim3(71, 1, 1), 256, 0, stream>>>(bf_upd, lam_w, lam_b, nullptr, lm_rm,
                                                  N_ * A_, H_, D_, 0, 0, 0);
  // 8. qh = (bf_upd + anchor_embed) @ wq + bq   (fused add)
  gemm_mfma<<<dim3(71, 4, 1), 256, 0, stream>>>(bf_upd, anchor_embed, wq, bq, nullptr, qhb,
                                                N_ * A_, D_, D_, 0, 0, 0);
  // 9. kh = key_in @ wk + bk
  gemm_mfma<<<dim3(94, 4, 1), 256, 0, stream>>>(key_in, nullptr, wk, bk, nullptr, kh_rm,
                                                N_ * M_, D_, D_, 0, 0, 0);
  // 10. vh = key_feat @ wv + bv
  gemm_mfma<<<dim3(94, 4, 1), 256, 0, stream>>>(key_feat, nullptr, wv, bv, nullptr, vh_rm,
                                                N_ * M_, D_, D_, 0, 0, 0);
  // 11. flash attention (bias on the fly)
  attn_kernel<<<dim3((A_ + QT_ - 1) / QT_, N_ * H_), 512, 0, stream>>>(qhb, kh_rm, vh_rm,
                                                                       lm_rm, b_anchor, i2j_rm, att_out);
  // 12. out projection + residual
  gemm_mfma<<<dim3(71, 4, 1), 256, 0, stream>>>(att_out, nullptr, wo, bo, bf_upd, res_buf,
                                                N_ * A_, D_, D_, 0, 0, 0);
  // 13. LayerNorm -> d_out
  ln_kernel<<<N_ * A_, 256, 0, stream>>>(res_buf, ln_g, ln_b, (float*)d_out);
}

// Round 5
// 550.602 us; speedup vs baseline: 2.2548x; 1.4269x over previous
//
#include <hip/hip_runtime.h>
#include <math.h>

#define N_ 5
#define A_ 900
#define AD_ 8
#define D_ 256
#define H_ 8
#define DH_ 32
#define K_ 300
#define NM1_ 4
#define M_ 1200   // K_*(N_-1)
#define KC_ 64    // attn key chunk
#define NCHUNK_ 19  // ceil(1200/64)

typedef _Float16 f16x8 __attribute__((ext_vector_type(8)));
typedef float f32x4 __attribute__((ext_vector_type(4)));

// ---------------- scores: sigmoid(b_feature @ w_roi + b_roi) ----------------
__global__ __launch_bounds__(256) void score_kernel(const float* __restrict__ bf,
                                                    const float* __restrict__ w,
                                                    const float* __restrict__ b,
                                                    float* __restrict__ scores) {
  int wid = threadIdx.x >> 6, lane = threadIdx.x & 63;
  int row = blockIdx.x * 4 + wid;
  if (row >= N_ * A_) return;
  const float* x = bf + (long)row * D_;
  float dot = 0.f;
#pragma unroll
  for (int t = 0; t < 4; t++) dot += x[lane + 64 * t] * w[lane + 64 * t];
#pragma unroll
  for (int o = 32; o; o >>= 1) dot += __shfl_xor(dot, o, 64);
  if (lane == 0) scores[row] = 1.0f / (1.0f + expf(-(dot + b[0])));
}

// ---------------- top-k via bitonic sort (1 block per batch row) ----------------
__global__ __launch_bounds__(1024) void topk_kernel(const float* __restrict__ scores,
                                                    int* __restrict__ top_idx,
                                                    float* __restrict__ conf) {
  __shared__ float sc[1024];
  __shared__ int si[1024];
  int i = blockIdx.x, t = threadIdx.x;
  sc[t] = (t < A_) ? scores[i * A_ + t] : -INFINITY;
  si[t] = t;
  __syncthreads();
  for (int k = 2; k <= 1024; k <<= 1) {
    for (int j = k >> 1; j > 0; j >>= 1) {
      int ixj = t ^ j;
      if (ixj > t) {
        bool dir = ((t & k) == 0);
        float a = sc[t], b = sc[ixj];
        bool sw = dir ? (a < b) : (a > b);
        if (sw) {
          sc[t] = b; sc[ixj] = a;
          int tmp = si[t]; si[t] = si[ixj]; si[ixj] = tmp;
        }
      }
      __syncthreads();
    }
  }
  if (t < K_) {
    top_idx[i * K_ + t] = si[t];
    conf[i * K_ + t] = sc[t] > 0.5f ? 1.0f : 0.0f;
  }
}

// ---------------- tiny MLP: one block per transform row ----------------
__global__ __launch_bounds__(256) void mlp_kernel(const float* __restrict__ tm,
                                                  const float* __restrict__ bn_g, const float* __restrict__ bn_b,
                                                  const float* __restrict__ fc1_w, const float* __restrict__ fc1_b,
                                                  const float* __restrict__ fc2_w, const float* __restrict__ fc2_b,
                                                  float* __restrict__ t_out) {
  int r = blockIdx.x;  // 0..19
  int t = threadIdx.x;
  __shared__ float x[20][12];
  __shared__ float y[12];
  __shared__ float hbuf[D_];
  if (t < 240) {
    int rr = t / 12, f = t % 12;
    int i = rr / NM1_, jj = rr % NM1_;
    int j = jj < i ? jj : jj + 1;
    int r4 = f / 4, c4 = f % 4;
    x[rr][f] = tm[((long)(i * N_ + j) * 4 + r4) * 4 + c4];
  }
  __syncthreads();
  if (t < 12) {
    float s = 0.f;
    for (int rr = 0; rr < 20; rr++) s += x[rr][t];
    float m = s / 20.0f;
    float v = 0.f;
    for (int rr = 0; rr < 20; rr++) { float d = x[rr][t] - m; v += d * d; }
    v /= 20.0f;
    y[t] = (x[r][t] - m) * rsqrtf(v + 1e-5f) * bn_g[t] + bn_b[t];
  }
  __syncthreads();
  float acc = fc1_b[t];
#pragma unroll
  for (int f = 0; f < 12; f++) acc += y[f] * fc1_w[f * D_ + t];
  hbuf[t] = fmaxf(acc, 0.0f);
  __syncthreads();
  float acc2 = fc2_b[t];
  for (int k = 0; k < D_; k++) acc2 += hbuf[k] * fc2_w[k * D_ + t];
  t_out[r * D_ + t] = acc2;
}

// ---------------- gather: key_feat, i2j_rm, conf_rm, key_in (k-parallel) ----------------
#define GKT_ 30
__global__ __launch_bounds__(256) void gather_kernel(const float* __restrict__ b_feature,
                                                     const float* __restrict__ i2j_anchor,
                                                     const int* __restrict__ top_idx,
                                                     const float* __restrict__ conf,
                                                     const float* __restrict__ anc_w,
                                                     const float* __restrict__ anc_b,
                                                     const float* __restrict__ t_mlp,
                                                     float* __restrict__ key_feat,
                                                     float* __restrict__ conf_rm,
                                                     float* __restrict__ i2j_rm,
                                                     float* __restrict__ key_in) {
  int blk = blockIdx.x;  // i*4+jj
  int i = blk / NM1_, jj = blk % NM1_;
  int j = jj < i ? jj : jj + 1;
  int k0 = blockIdx.y * GKT_;
  int c = threadIdx.x;
  __shared__ float aw[AD_][D_];
#pragma unroll
  for (int r = 0; r < AD_; r++) aw[r][c] = anc_w[r * D_ + c];
  float ab = anc_b[c];
  float tv = t_mlp[(i * NM1_ + jj) * D_ + c];
  __syncthreads();
  for (int k = k0; k < k0 + GKT_; k++) {
    int idx = top_idx[j * K_ + k];
    float cf = conf[j * K_ + k];
    const float* src = b_feature + ((long)(j * A_ + idx)) * D_;
    float val = src[c];
    long mrow = (long)i * M_ + jj * K_ + k;
    key_feat[mrow * D_ + c] = val;
    const float* ap = i2j_anchor + ((long)((i * N_ + j) * A_ + idx)) * AD_;
    if (c < AD_) i2j_rm[mrow * AD_ + c] = ap[c];
    if (c == 0) conf_rm[mrow] = cf;
    float pos = ab + tv;
#pragma unroll
    for (int r = 0; r < AD_; r++) pos += ap[r] * aw[r][c];
    key_in[mrow * D_ + c] = val + pos;
  }
}

// ---------------- inside mask (bbox inline, conf folded, fp16 out) ----------------
__global__ __launch_bounds__(256) void inside_kernel(const float* __restrict__ i2j_rm,
                                                     const float* __restrict__ conf_rm,
                                                     const float* __restrict__ ban,
                                                     _Float16* __restrict__ inside) {
  int row = blockIdx.x;  // i*900+a
  int i = row / A_;
  const float* ap = ban + (long)row * AD_;
  float x = ap[0], y = ap[1], z = ap[2];
  float w = expf(ap[3]), l = expf(ap[4]), hh = expf(ap[5]);
  float yaw = atan2f(ap[6], ap[7]);
  float ca = fabsf(cosf(yaw)), sa = fabsf(sinf(yaw));
  float ex = 0.5f * (l * ca + w * sa);
  float ey = 0.5f * (l * sa + w * ca);
  float ez = 0.5f * hh;
  float mn0 = x - ex, mn1 = y - ey, mn2 = z - ez;
  float mx0 = x + ex, mx1 = y + ey, mx2 = z + ez;
#pragma unroll
  for (int it = 0; it < 5; it++) {
    int m = it * 256 + threadIdx.x;
    if (m < M_) {
      const float* cp = i2j_rm + ((long)i * M_ + m) * AD_;
      float c0 = cp[0], c1 = cp[1], c2 = cp[2];
      bool ins = (c0 >= mn0) && (c0 <= mx0) && (c1 >= mn1) && (c1 <= mx1) && (c2 >= mn2) && (c2 <= mx2);
      inside[(long)row * M_ + m] = ins ? (_Float16)conf_rm[(long)i * M_ + m] : (_Float16)0.0f;
    }
  }
}

// ---------------- fp32 SIMT GEMM (tiny lam projection, N=8) ----------------
__global__ __launch_bounds__(256) void gemm_kernel(const float* __restrict__ A,
                                                   const float* __restrict__ B,
                                                   const float* __restrict__ bias,
                                                   const float* __restrict__ res,
                                                   float* __restrict__ C,
                                                   int Mr, int Nc, int Kc,
                                                   long sA, long sB, long sC) {
  int bz = blockIdx.z;
  A += (long)bz * sA;
  B += (long)bz * sB;
  C += (long)bz * sC;
  if (res) res += (long)bz * sC;
  __shared__ float As[16][65];
  __shared__ float Bs[16][65];
  int m0 = blockIdx.x * 64, n0 = blockIdx.y * 64;
  int tid = threadIdx.x;
  int tx = tid % 16, ty = tid / 16;
  float acc[4][4] = {};
  for (int k0 = 0; k0 < Kc; k0 += 16) {
#pragma unroll
    for (int r = 0; r < 4; r++) {
      int l = r * 256 + tid;
      int mm = l >> 4, kk = l & 15;
      int gm = m0 + mm, gk = k0 + kk;
      As[kk][mm] = (gm < Mr && gk < Kc) ? A[(long)gm * Kc + gk] : 0.0f;
    }
#pragma unroll
    for (int r = 0; r < 4; r++) {
      int l = r * 256 + tid;
      int nn = l & 63, kk = l >> 6;
      int gk = k0 + kk, gn = n0 + nn;
      Bs[kk][nn] = (gk < Kc && gn < Nc) ? B[(long)gk * Nc + gn] : 0.0f;
    }
    __syncthreads();
#pragma unroll
    for (int kk = 0; kk < 16; kk++) {
      float av[4], bv[4];
#pragma unroll
      for (int ii = 0; ii < 4; ii++) av[ii] = As[kk][ty * 4 + ii];
#pragma unroll
      for (int jjv = 0; jjv < 4; jjv++) bv[jjv] = Bs[kk][tx * 4 + jjv];
#pragma unroll
      for (int ii = 0; ii < 4; ii++)
#pragma unroll
        for (int jjv = 0; jjv < 4; jjv++) acc[ii][jjv] += av[ii] * bv[jjv];
    }
    __syncthreads();
  }
#pragma unroll
  for (int ii = 0; ii < 4; ii++) {
    int gm = m0 + ty * 4 + ii;
    if (gm >= Mr) continue;
#pragma unroll
    for (int jjv = 0; jjv < 4; jjv++) {
      int gn = n0 + tx * 4 + jjv;
      if (gn >= Nc) continue;
      float v = acc[ii][jjv];
      if (bias) v += bias[gn];
      if (res) v += res[(long)gm * Nc + gn];
      C[(long)gm * Nc + gn] = v;
    }
  }
}

// ---------------- MFMA fp16 GEMM: C = (A[+A2])@B (+bias) (+res) ----------------
// TA: A element type (float or _Float16). TO: output type.
#define BM_ 64
#define BN_ 64
#define BK_ 32
#define LDK_ 40
template <typename TA, typename TO>
__global__ __launch_bounds__(256) void gemm_mfma(const TA* __restrict__ A,
                                                 const float* __restrict__ A2,
                                                 const float* __restrict__ B,
                                                 const float* __restrict__ bias,
                                                 const float* __restrict__ res,
                                                 TO* __restrict__ C,
                                                 int Mr, int Nc, int Kc,
                                                 long sA, long sB, long sC) {
  int bz = blockIdx.z;
  A += (long)bz * sA;
  if (A2) A2 += (long)bz * sA;
  B += (long)bz * sB;
  C += (long)bz * sC;
  if (res) res += (long)bz * sC;
  __shared__ _Float16 As[BM_ * LDK_];
  __shared__ _Float16 Bt[BN_ * LDK_];
  int m0 = blockIdx.x * BM_, n0 = blockIdx.y * BN_;
  int tid = threadIdx.x;
  int wid = tid >> 6, lane = tid & 63;
  int wr = (wid >> 1) * 32, wc = (wid & 1) * 32;
  int lr = lane & 15;
  int lk = (lane >> 4) * 8;
  f32x4 acc[2][2] = {};
  for (int k0 = 0; k0 < Kc; k0 += BK_) {
#pragma unroll
    for (int r = 0; r < 8; r++) {
      int idx = r * 256 + tid;
      int mm = idx >> 5, kk = idx & 31;
      int gm = m0 + mm, gk = k0 + kk;
      float v = 0.0f;
      if (gm < Mr && gk < Kc) {
        v = (float)A[(long)gm * Kc + gk];
        if (A2) v += A2[(long)gm * Kc + gk];
      }
      As[mm * LDK_ + kk] = (_Float16)v;
    }
#pragma unroll
    for (int r = 0; r < 8; r++) {
      int idx = r * 256 + tid;
      int kk = idx >> 6, nn = idx & 63;
      int gk = k0 + kk, gn = n0 + nn;
      float v = (gk < Kc && gn < Nc) ? B[(long)gk * Nc + gn] : 0.0f;
      Bt[nn * LDK_ + kk] = (_Float16)v;
    }
    __syncthreads();
    f16x8 af[2], bf[2];
#pragma unroll
    for (int mi = 0; mi < 2; mi++) af[mi] = *(const f16x8*)&As[(wr + mi * 16 + lr) * LDK_ + lk];
#pragma unroll
    for (int ni = 0; ni < 2; ni++) bf[ni] = *(const f16x8*)&Bt[(wc + ni * 16 + lr) * LDK_ + lk];
#pragma unroll
    for (int mi = 0; mi < 2; mi++)
#pragma unroll
      for (int ni = 0; ni < 2; ni++)
        acc[mi][ni] = __builtin_amdgcn_mfma_f32_16x16x32_f16(af[mi], bf[ni], acc[mi][ni], 0, 0, 0);
    __syncthreads();
  }
#pragma unroll
  for (int mi = 0; mi < 2; mi++) {
#pragma unroll
    for (int ni = 0; ni < 2; ni++) {
#pragma unroll
      for (int rr = 0; rr < 4; rr++) {
        int row = m0 + wr + mi * 16 + (lane >> 4) * 4 + rr;
        int col = n0 + wc + ni * 16 + (lane & 15);
        if (row < Mr && col < Nc) {
          float v = acc[mi][ni][rr];
          if (bias) v += bias[col];
          if (res) v += res[(long)row * Nc + col];
          C[(long)row * Nc + col] = (TO)v;
        }
      }
    }
  }
}

// ---------------- MFMA flash attention ----------------
// Block: one (i,h) x 64-query tile. 4 waves x 16 q each. K-chunks of 64.
__global__ __launch_bounds__(256) void attn_mfma(const _Float16* __restrict__ qh16,
                                                 const _Float16* __restrict__ kh16,
                                                 const _Float16* __restrict__ vh16,
                                                 const float* __restrict__ lm_rm,
                                                 const float* __restrict__ ban,
                                                 const float* __restrict__ i2j_rm,
                                                 float* __restrict__ out) {
  int qt = blockIdx.x;          // 0..14
  int ih = blockIdx.y;          // i*8+h
  int i = ih >> 3, h = ih & 7;
  int a0 = qt * 64;

  __shared__ _Float16 Qs[64][40];
  __shared__ _Float16 Ks[64][40];
  __shared__ _Float16 Vt[32][72];   // [d][m]
  __shared__ _Float16 Ps[64][72];   // per-wave 16-row slices
  __shared__ float axs[64], ays[64], lmvs[64], cxs[64], cys[64];

  int tid = threadIdx.x;
  int lane = tid & 63;
  int w16 = (tid >> 6) * 16;
  int lr = lane & 15;
  int lk = (lane >> 4) * 8;
  int srow = tid >> 2, spiece = tid & 3;

  // stage Q + per-query scalars
  {
    int aq = a0 + srow;
    int a_ld = aq < A_ ? aq : A_ - 1;
    const uint4* src = (const uint4*)(qh16 + ((long)(i * A_ + a_ld) * D_ + h * DH_));
    *(uint4*)&Qs[srow][spiece * 8] = src[spiece];
  }
  if (tid < 64) {
    int aq = a0 + tid;
    int a_ld = aq < A_ ? aq : A_ - 1;
    axs[tid] = ban[(long)(i * A_ + a_ld) * AD_ + 0];
    ays[tid] = ban[(long)(i * A_ + a_ld) * AD_ + 1];
    lmvs[tid] = lm_rm[(long)(i * A_ + a_ld) * H_ + h];
  }
  __syncthreads();

  // hoisted per-row constants (rows 4*(lane>>4)+r within this wave's 16)
  float axr[4], ayr[4], lmr[4];
#pragma unroll
  for (int r = 0; r < 4; r++) {
    int qrow = w16 + (lane >> 4) * 4 + r;
    axr[r] = axs[qrow]; ayr[r] = ays[qrow]; lmr[r] = lmvs[qrow];
  }
  f16x8 qa = *(const f16x8*)&Qs[w16 + lr][lk];

  float m_run[4], s_part[4];
  f32x4 oacc[2] = {};
#pragma unroll
  for (int r = 0; r < 4; r++) { m_run[r] = -INFINITY; s_part[r] = 0.0f; }

  const _Float16* kb = kh16 + (long)i * M_ * D_ + h * DH_;
  const _Float16* vb = vh16 + (long)i * M_ * D_ + h * DH_;

  for (int c = 0; c < NCHUNK_; c++) {
    int m0 = c * KC_;
    __syncthreads();
    // stage K chunk + V chunk (transposed)
    {
      int mrow = m0 + srow;
      uint4 kv, vv;
      if (mrow < M_) {
        kv = ((const uint4*)(kb + (long)mrow * D_))[spiece];
        vv = ((const uint4*)(vb + (long)mrow * D_))[spiece];
      } else {
        kv = make_uint4(0, 0, 0, 0);
        vv = make_uint4(0, 0, 0, 0);
      }
      *(uint4*)&Ks[srow][spiece * 8] = kv;
      const _Float16* hp = (const _Float16*)&vv;
#pragma unroll
      for (int e = 0; e < 8; e++) Vt[spiece * 8 + e][srow] = hp[e];
    }
    if (tid < 64) {
      int mr = m0 + tid;
      int mc = mr < M_ ? mr : M_ - 1;
      cxs[tid] = i2j_rm[((long)i * M_ + mc) * AD_ + 0];
      cys[tid] = i2j_rm[((long)i * M_ + mc) * AD_ + 1];
    }
    __syncthreads();

    // QK^T: 16q x 64m per wave
    f32x4 sacc[4];
#pragma unroll
    for (int mb = 0; mb < 4; mb++) {
      f16x8 kf = *(const f16x8*)&Ks[mb * 16 + lr][lk];
      sacc[mb] = __builtin_amdgcn_mfma_f32_16x16x32_f16(qa, kf, (f32x4){0.f, 0.f, 0.f, 0.f}, 0, 0, 0);
    }

    // bias + online softmax (S layout: row=(lane>>4)*4+r, col=lane&15)
    float lg[4][4];  // [mb][r]
#pragma unroll
    for (int mb = 0; mb < 4; mb++) {
      int mcol = m0 + mb * 16 + (lane & 15);
      float cx = cxs[mb * 16 + (lane & 15)];
      float cy = cys[mb * 16 + (lane & 15)];
      bool valid = (mcol < M_);
#pragma unroll
      for (int r = 0; r < 4; r++) {
        float dx = axr[r] - cx, dy = ayr[r] - cy;
        float L = __logf(1.0f + sqrtf(dx * dx + dy * dy + 1e-12f));
        float v = sacc[mb][r] * 0.17677669529663687f - L * lmr[r];
        lg[mb][r] = valid ? v : -INFINITY;
      }
    }
#pragma unroll
    for (int r = 0; r < 4; r++) {
      float cm = fmaxf(fmaxf(lg[0][r], lg[1][r]), fmaxf(lg[2][r], lg[3][r]));
#pragma unroll
      for (int o = 1; o < 16; o <<= 1) cm = fmaxf(cm, __shfl_xor(cm, o, 64));
      float nm = fmaxf(m_run[r], cm);
      float corr = __expf(m_run[r] - nm);
      s_part[r] *= corr;
      oacc[0][r] *= corr;
      oacc[1][r] *= corr;
      m_run[r] = nm;
      float ps = 0.0f;
#pragma unroll
      for (int mb = 0; mb < 4; mb++) {
        float p = __expf(lg[mb][r] - nm);
        ps += p;
        Ps[w16 + (lane >> 4) * 4 + r][mb * 16 + (lane & 15)] = (_Float16)p;
      }
      s_part[r] += ps;
    }

    // PV: A = Ps (row=q, k=m), B = Vt (col=d, k=m)
#pragma unroll
    for (int ks = 0; ks < 2; ks++) {
      f16x8 pa = *(const f16x8*)&Ps[w16 + lr][ks * 32 + lk];
#pragma unroll
      for (int db = 0; db < 2; db++) {
        f16x8 vf = *(const f16x8*)&Vt[db * 16 + lr][ks * 32 + lk];
        oacc[db] = __builtin_amdgcn_mfma_f32_16x16x32_f16(pa, vf, oacc[db], 0, 0, 0);
      }
    }
  }

  // finalize: reduce s across the 16 col-lanes, write out
  float inv[4];
#pragma unroll
  for (int r = 0; r < 4; r++) {
    float st = s_part[r];
#pragma unroll
    for (int o = 1; o < 16; o <<= 1) st += __shfl_xor(st, o, 64);
    inv[r] = 1.0f / st;
  }
#pragma unroll
  for (int db = 0; db < 2; db++) {
#pragma unroll
    for (int r = 0; r < 4; r++) {
      int a = a0 + w16 + (lane >> 4) * 4 + r;
      if (a < A_) out[((long)(i * A_ + a)) * D_ + h * DH_ + db * 16 + (lane & 15)] = oacc[db][r] * inv[r];
    }
  }
}

// ---------------- LayerNorm ----------------
__global__ __launch_bounds__(256) void ln_kernel(const float* __restrict__ x,
                                                 const float* __restrict__ g,
                                                 const float* __restrict__ b,
                                                 float* __restrict__ out) {
  int row = blockIdx.x;
  int t = threadIdx.x;
  float v = x[(long)row * D_ + t];
  float s = v, sq = v * v;
#pragma unroll
  for (int o = 32; o; o >>= 1) {
    s += __shfl_xor(s, o, 64);
    sq += __shfl_xor(sq, o, 64);
  }
  __shared__ float ss[4], ssq[4];
  int wid = t >> 6, lane = t & 63;
  if (lane == 0) { ss[wid] = s; ssq[wid] = sq; }
  __syncthreads();
  float ts = ss[0] + ss[1] + ss[2] + ss[3];
  float tq = ssq[0] + ssq[1] + ssq[2] + ssq[3];
  float mean = ts / (float)D_;
  float var = tq / (float)D_ - mean * mean;
  out[(long)row * D_ + t] = (v - mean) * rsqrtf(var + 1e-5f) * g[t] + b[t];
}

extern "C" void kernel_launch(void* const* d_in, const int* in_sizes, int n_in,
                              void* d_out, int out_size, void* d_ws, size_t ws_size,
                              hipStream_t stream) {
  const float* i2j_anchor   = (const float*)d_in[0];
  const float* b_anchor     = (const float*)d_in[1];
  const float* b_feature    = (const float*)d_in[2];
  const float* tm           = (const float*)d_in[3];
  const float* anchor_embed = (const float*)d_in[4];
  const float* w_roi  = (const float*)d_in[5];
  const float* b_roi  = (const float*)d_in[6];
  const float* bn_g   = (const float*)d_in[7];
  const float* bn_b   = (const float*)d_in[8];
  const float* fc1_w  = (const float*)d_in[9];
  const float* fc1_b  = (const float*)d_in[10];
  const float* fc2_w  = (const float*)d_in[11];
  const float* fc2_b  = (const float*)d_in[12];
  const float* anc_w  = (const float*)d_in[13];
  const float* anc_b  = (const float*)d_in[14];
  const float* lam_w  = (const float*)d_in[15];
  const float* lam_b  = (const float*)d_in[16];
  const float* wq = (const float*)d_in[17];
  const float* bq = (const float*)d_in[18];
  const float* wk = (const float*)d_in[19];
  const float* bk = (const float*)d_in[20];
  const float* wv = (const float*)d_in[21];
  const float* bv = (const float*)d_in[22];
  const float* wo = (const float*)d_in[23];
  const float* bo = (const float*)d_in[24];
  const float* ln_g = (const float*)d_in[25];
  const float* ln_b = (const float*)d_in[26];

  float* ws = (float*)d_ws;
  size_t off = 0;
  auto alloc = [&](size_t n) { float* p = ws + off; off += n; return p; };

  float* scores    = alloc(N_ * A_);
  int*   top_idx   = (int*)alloc(N_ * K_);
  float* conf      = alloc(N_ * K_);
  float* t_mlp     = alloc(20 * D_);
  float* key_feat  = alloc((size_t)N_ * M_ * D_);
  float* conf_rm   = alloc((size_t)N_ * M_);
  float* i2j_rm    = alloc((size_t)N_ * M_ * AD_);
  float* key_in    = alloc((size_t)N_ * M_ * D_);
  _Float16* inside16 = (_Float16*)alloc((size_t)N_ * A_ * M_ / 2);
  float* bf_upd    = alloc((size_t)N_ * A_ * D_);
  _Float16* qh16   = (_Float16*)alloc((size_t)N_ * A_ * D_ / 2);
  _Float16* kh16   = (_Float16*)alloc((size_t)N_ * M_ * D_ / 2);
  _Float16* vh16   = (_Float16*)alloc((size_t)N_ * M_ * D_ / 2);
  float* lm_rm     = alloc((size_t)N_ * A_ * H_);
  float* att_out   = alloc((size_t)N_ * A_ * D_);
  float* res_buf   = alloc((size_t)N_ * A_ * D_);

  // 1. scores
  score_kernel<<<(N_ * A_ + 3) / 4, 256, 0, stream>>>(b_feature, w_roi, b_roi, scores);
  // 2. top-k
  topk_kernel<<<N_, 1024, 0, stream>>>(scores, top_idx, conf);
  // 3. tiny MLP
  mlp_kernel<<<20, 256, 0, stream>>>(tm, bn_g, bn_b, fc1_w, fc1_b, fc2_w, fc2_b, t_mlp);
  // 4. gather
  gather_kernel<<<dim3(N_ * NM1_, K_ / GKT_), 256, 0, stream>>>(b_feature, i2j_anchor, top_idx, conf,
                                                                anc_w, anc_b, t_mlp,
                                                                key_feat, conf_rm, i2j_rm, key_in);
  // 5. inside mask (fp16)
  inside_kernel<<<N_ * A_, 256, 0, stream>>>(i2j_rm, conf_rm, b_anchor, inside16);
  // 6. agg GEMM: bf_upd = inside @ key_feat + b_feature
  gemm_mfma<_Float16, float><<<dim3(15, 4, N_), 256, 0, stream>>>(
      inside16, nullptr, key_feat, nullptr, b_feature, bf_upd,
      A_, D_, M_, (long)A_ * M_, (long)M_ * D_, (long)A_ * D_);
  // 7. lm = bf_upd @ lam_w + lam_b
  gemm_kernel<<<dim3(71, 1, 1), 256, 0, stream>>>(bf_upd, lam_w, lam_b, nullptr, lm_rm,
                                                  N_ * A_, H_, D_, 0, 0, 0);
  // 8. qh16 = (bf_upd + anchor_embed) @ wq + bq
  gemm_mfma<float, _Float16><<<dim3(71, 4, 1), 256, 0, stream>>>(
      bf_upd, anchor_embed, wq, bq, nullptr, qh16, N_ * A_, D_, D_, 0, 0, 0);
  // 9. kh16 = key_in @ wk + bk
  gemm_mfma<float, _Float16><<<dim3(94, 4, 1), 256, 0, stream>>>(
      key_in, nullptr, wk, bk, nullptr, kh16, N_ * M_, D_, D_, 0, 0, 0);
  // 10. vh16 = key_feat @ wv + bv
  gemm_mfma<float, _Float16><<<dim3(94, 4, 1), 256, 0, stream>>>(
      key_feat, nullptr, wv, bv, nullptr, vh16, N_ * M_, D_, D_, 0, 0, 0);
  // 11. MFMA flash attention
  attn_mfma<<<dim3(15, N_ * H_), 256, 0, stream>>>(qh16, kh16, vh16, lm_rm, b_anchor, i2j_rm, att_out);
  // 12. out projection + residual
  gemm_mfma<float, float><<<dim3(71, 4, 1), 256, 0, stream>>>(
      att_out, nullptr, wo, bo, bf_upd, res_buf, N_ * A_, D_, D_, 0, 0, 0);
  // 13. LayerNorm -> d_out
  ln_kernel<<<N_ * A_, 256, 0, stream>>>(res_buf, ln_g, ln_b, (float*)d_out);
}

// Round 6
// 220.339 us; speedup vs baseline: 5.6344x; 2.4989x over previous
//
#include <hip/hip_runtime.h>
#include <math.h>

#define N_ 5
#define A_ 900
#define AD_ 8
#define D_ 256
#define H_ 8
#define DH_ 32
#define K_ 300
#define NM1_ 4
#define M_ 1200   // K_*(N_-1)
#define KC_ 64    // attn key chunk
#define NCHUNK_ 19

typedef _Float16 f16x8 __attribute__((ext_vector_type(8)));
typedef _Float16 f16x4 __attribute__((ext_vector_type(4)));
typedef float f32x4 __attribute__((ext_vector_type(4)));

// ---------------- scores ----------------
__global__ __launch_bounds__(256) void score_kernel(const float* __restrict__ bf,
                                                    const float* __restrict__ w,
                                                    const float* __restrict__ b,
                                                    float* __restrict__ scores) {
  int wid = threadIdx.x >> 6, lane = threadIdx.x & 63;
  int row = blockIdx.x * 4 + wid;
  if (row >= N_ * A_) return;
  const float* x = bf + (long)row * D_;
  float dot = 0.f;
#pragma unroll
  for (int t = 0; t < 4; t++) dot += x[lane + 64 * t] * w[lane + 64 * t];
#pragma unroll
  for (int o = 32; o; o >>= 1) dot += __shfl_xor(dot, o, 64);
  if (lane == 0) scores[row] = 1.0f / (1.0f + expf(-(dot + b[0])));
}

// ---------------- top-k ----------------
__global__ __launch_bounds__(1024) void topk_kernel(const float* __restrict__ scores,
                                                    int* __restrict__ top_idx,
                                                    float* __restrict__ conf) {
  __shared__ float sc[1024];
  __shared__ int si[1024];
  int i = blockIdx.x, t = threadIdx.x;
  sc[t] = (t < A_) ? scores[i * A_ + t] : -INFINITY;
  si[t] = t;
  __syncthreads();
  for (int k = 2; k <= 1024; k <<= 1) {
    for (int j = k >> 1; j > 0; j >>= 1) {
      int ixj = t ^ j;
      if (ixj > t) {
        bool dir = ((t & k) == 0);
        float a = sc[t], b = sc[ixj];
        bool sw = dir ? (a < b) : (a > b);
        if (sw) {
          sc[t] = b; sc[ixj] = a;
          int tmp = si[t]; si[t] = si[ixj]; si[ixj] = tmp;
        }
      }
      __syncthreads();
    }
  }
  if (t < K_) {
    top_idx[i * K_ + t] = si[t];
    conf[i * K_ + t] = sc[t] > 0.5f ? 1.0f : 0.0f;
  }
}

// ---------------- tiny MLP ----------------
__global__ __launch_bounds__(256) void mlp_kernel(const float* __restrict__ tm,
                                                  const float* __restrict__ bn_g, const float* __restrict__ bn_b,
                                                  const float* __restrict__ fc1_w, const float* __restrict__ fc1_b,
                                                  const float* __restrict__ fc2_w, const float* __restrict__ fc2_b,
                                                  float* __restrict__ t_out) {
  int r = blockIdx.x;
  int t = threadIdx.x;
  __shared__ float x[20][12];
  __shared__ float y[12];
  __shared__ float hbuf[D_];
  if (t < 240) {
    int rr = t / 12, f = t % 12;
    int i = rr / NM1_, jj = rr % NM1_;
    int j = jj < i ? jj : jj + 1;
    int r4 = f / 4, c4 = f % 4;
    x[rr][f] = tm[((long)(i * N_ + j) * 4 + r4) * 4 + c4];
  }
  __syncthreads();
  if (t < 12) {
    float s = 0.f;
    for (int rr = 0; rr < 20; rr++) s += x[rr][t];
    float m = s / 20.0f;
    float v = 0.f;
    for (int rr = 0; rr < 20; rr++) { float d = x[rr][t] - m; v += d * d; }
    v /= 20.0f;
    y[t] = (x[r][t] - m) * rsqrtf(v + 1e-5f) * bn_g[t] + bn_b[t];
  }
  __syncthreads();
  float acc = fc1_b[t];
#pragma unroll
  for (int f = 0; f < 12; f++) acc += y[f] * fc1_w[f * D_ + t];
  hbuf[t] = fmaxf(acc, 0.0f);
  __syncthreads();
  float acc2 = fc2_b[t];
  for (int k = 0; k < D_; k++) acc2 += hbuf[k] * fc2_w[k * D_ + t];
  t_out[r * D_ + t] = acc2;
}

// ---------------- gather (fp16 outputs) ----------------
#define GKT_ 30
__global__ __launch_bounds__(256) void gather_kernel(const float* __restrict__ b_feature,
                                                     const float* __restrict__ i2j_anchor,
                                                     const int* __restrict__ top_idx,
                                                     const float* __restrict__ conf,
                                                     const float* __restrict__ anc_w,
                                                     const float* __restrict__ anc_b,
                                                     const float* __restrict__ t_mlp,
                                                     _Float16* __restrict__ key_feat16,
                                                     float* __restrict__ conf_rm,
                                                     float* __restrict__ i2j_rm,
                                                     _Float16* __restrict__ key_in16) {
  int blk = blockIdx.x;
  int i = blk / NM1_, jj = blk % NM1_;
  int j = jj < i ? jj : jj + 1;
  int k0 = blockIdx.y * GKT_;
  int c = threadIdx.x;
  __shared__ float aw[AD_][D_];
#pragma unroll
  for (int r = 0; r < AD_; r++) aw[r][c] = anc_w[r * D_ + c];
  float ab = anc_b[c];
  float tv = t_mlp[(i * NM1_ + jj) * D_ + c];
  __syncthreads();
  for (int k = k0; k < k0 + GKT_; k++) {
    int idx = top_idx[j * K_ + k];
    float cf = conf[j * K_ + k];
    const float* src = b_feature + ((long)(j * A_ + idx)) * D_;
    float val = src[c];
    long mrow = (long)i * M_ + jj * K_ + k;
    key_feat16[mrow * D_ + c] = (_Float16)val;
    const float* ap = i2j_anchor + ((long)((i * N_ + j) * A_ + idx)) * AD_;
    if (c < AD_) i2j_rm[mrow * AD_ + c] = ap[c];
    if (c == 0) conf_rm[mrow] = cf;
    float pos = ab + tv;
#pragma unroll
    for (int r = 0; r < AD_; r++) pos += ap[r] * aw[r][c];
    key_in16[mrow * D_ + c] = (_Float16)(val + pos);
  }
}

// ---------------- inside mask (fp16) ----------------
__global__ __launch_bounds__(256) void inside_kernel(const float* __restrict__ i2j_rm,
                                                     const float* __restrict__ conf_rm,
                                                     const float* __restrict__ ban,
                                                     _Float16* __restrict__ inside) {
  int row = blockIdx.x;
  int i = row / A_;
  const float* ap = ban + (long)row * AD_;
  float x = ap[0], y = ap[1], z = ap[2];
  float w = expf(ap[3]), l = expf(ap[4]), hh = expf(ap[5]);
  float yaw = atan2f(ap[6], ap[7]);
  float ca = fabsf(cosf(yaw)), sa = fabsf(sinf(yaw));
  float ex = 0.5f * (l * ca + w * sa);
  float ey = 0.5f * (l * sa + w * ca);
  float ez = 0.5f * hh;
  float mn0 = x - ex, mn1 = y - ey, mn2 = z - ez;
  float mx0 = x + ex, mx1 = y + ey, mx2 = z + ez;
#pragma unroll
  for (int it = 0; it < 5; it++) {
    int m = it * 256 + threadIdx.x;
    if (m < M_) {
      const float* cp = i2j_rm + ((long)i * M_ + m) * AD_;
      float c0 = cp[0], c1 = cp[1], c2 = cp[2];
      bool ins = (c0 >= mn0) && (c0 <= mx0) && (c1 >= mn1) && (c1 <= mx1) && (c2 >= mn2) && (c2 <= mx2);
      inside[(long)row * M_ + m] = ins ? (_Float16)conf_rm[(long)i * M_ + m] : (_Float16)0.0f;
    }
  }
}

// ---------------- weight transpose fp32 -> fp16 [N][K] ----------------
__global__ __launch_bounds__(256) void wtrans_kernel(const float* __restrict__ w0, const float* __restrict__ w1,
                                                     const float* __restrict__ w2, const float* __restrict__ w3,
                                                     _Float16* __restrict__ out) {
  const float* src = (blockIdx.y == 0) ? w0 : (blockIdx.y == 1) ? w1 : (blockIdx.y == 2) ? w2 : w3;
  _Float16* dst = out + (size_t)blockIdx.y * D_ * D_;
  int tile = blockIdx.x;            // 0..15
  int kr = (tile >> 2) * 64, nc = (tile & 3) * 64;
  __shared__ float lds[64][65];
  int t = threadIdx.x;
#pragma unroll
  for (int r = 0; r < 16; r++) {
    int row = r * 4 + (t >> 6), col = t & 63;
    lds[row][col] = src[(size_t)(kr + row) * D_ + nc + col];
  }
  __syncthreads();
#pragma unroll
  for (int r = 0; r < 16; r++) {
    int orow = r * 4 + (t >> 6), ocol = t & 63;
    dst[(size_t)(nc + orow) * D_ + kr + ocol] = (_Float16)lds[ocol][orow];
  }
}

// ---------------- key_feat16 transpose -> [i][256][1200] ----------------
__global__ __launch_bounds__(256) void kftrans_kernel(const _Float16* __restrict__ in, _Float16* __restrict__ out) {
  int i = blockIdx.z;
  int m0 = blockIdx.x * 64, d0 = blockIdx.y * 64;
  __shared__ _Float16 lds[64][66];
  int t = threadIdx.x;
  const _Float16* src = in + (size_t)i * M_ * D_;
  _Float16* dst = out + (size_t)i * D_ * M_;
#pragma unroll
  for (int r = 0; r < 16; r++) {
    int row = r * 4 + (t >> 6), col = t & 63;
    int m = m0 + row;
    lds[row][col] = (m < M_) ? src[(size_t)m * D_ + d0 + col] : (_Float16)0.0f;
  }
  __syncthreads();
#pragma unroll
  for (int r = 0; r < 16; r++) {
    int orow = r * 4 + (t >> 6), ocol = t & 63;
    int m = m0 + ocol;
    if (m < M_) dst[(size_t)(d0 + orow) * M_ + m] = lds[ocol][orow];
  }
}

// ---------------- shared 64x64 MFMA tile body (A,B both [row][k] fp16) ----------------
template <typename TO, bool HAS_BIAS, bool HAS_RES>
__device__ __forceinline__ void gemm_tile_body(
    const _Float16* __restrict__ A, int lda, int Mr,
    const _Float16* __restrict__ B, int ldb,
    const float* __restrict__ bias, const float* __restrict__ res,
    TO* __restrict__ C, int ldc,
    int m0, int n0, int k_begin, int k_end) {
  __shared__ _Float16 As[64 * 72];
  __shared__ _Float16 Bs[64 * 72];
  int tid = threadIdx.x;
  int lane = tid & 63;
  int wid = tid >> 6;
  int wr = (wid >> 1) * 32, wc = (wid & 1) * 32;
  int lr = lane & 15, lk = (lane >> 4) * 8;
  int srow = tid >> 3;          // 0..31
  int scol = (tid & 7) * 8;     // 0..56
  f16x8 aR[2], bR[2];
  f16x8 zero8 = {};
  auto loadg = [&](int kb) {
#pragma unroll
    for (int r = 0; r < 2; r++) {
      int gm = m0 + srow + r * 32;
      int gk = kb + scol;
      aR[r] = (gm < Mr && gk < k_end) ? *(const f16x8*)&A[(size_t)gm * lda + gk] : zero8;
      int gn = n0 + srow + r * 32;
      bR[r] = (gk < k_end) ? *(const f16x8*)&B[(size_t)gn * ldb + gk] : zero8;
    }
  };
  auto store_lds = [&]() {
#pragma unroll
    for (int r = 0; r < 2; r++) {
      *(f16x8*)&As[(srow + r * 32) * 72 + scol] = aR[r];
      *(f16x8*)&Bs[(srow + r * 32) * 72 + scol] = bR[r];
    }
  };
  f32x4 acc[2][2] = {};
  int niter = (k_end - k_begin + 63) >> 6;
  loadg(k_begin);
  store_lds();
  __syncthreads();
  for (int it = 0; it < niter; ++it) {
    bool more = (it + 1 < niter);
    if (more) loadg(k_begin + (it + 1) * 64);
#pragma unroll
    for (int ks = 0; ks < 2; ks++) {
      f16x8 af[2], bf[2];
#pragma unroll
      for (int mi = 0; mi < 2; mi++) af[mi] = *(const f16x8*)&As[(wr + mi * 16 + lr) * 72 + ks * 32 + lk];
#pragma unroll
      for (int ni = 0; ni < 2; ni++) bf[ni] = *(const f16x8*)&Bs[(wc + ni * 16 + lr) * 72 + ks * 32 + lk];
#pragma unroll
      for (int mi = 0; mi < 2; mi++)
#pragma unroll
        for (int ni = 0; ni < 2; ni++)
          acc[mi][ni] = __builtin_amdgcn_mfma_f32_16x16x32_f16(af[mi], bf[ni], acc[mi][ni], 0, 0, 0);
    }
    __syncthreads();
    if (more) { store_lds(); __syncthreads(); }
  }
#pragma unroll
  for (int mi = 0; mi < 2; mi++)
#pragma unroll
    for (int ni = 0; ni < 2; ni++)
#pragma unroll
      for (int rr = 0; rr < 4; rr++) {
        int row = m0 + wr + mi * 16 + (lane >> 4) * 4 + rr;
        int col = n0 + wc + ni * 16 + lr;
        if (row < Mr) {
          float v = acc[mi][ni][rr];
          if (HAS_BIAS) v += bias[col];
          if (HAS_RES) v += res[(size_t)row * ldc + col];
          C[(size_t)row * ldc + col] = (TO)v;
        }
      }
}

// ---------------- agg GEMM split-K: partial[sk][i][900][256] ----------------
__global__ __launch_bounds__(256) void agg_kernel(const _Float16* __restrict__ inside16,
                                                  const _Float16* __restrict__ kT16,
                                                  float* __restrict__ partial) {
  int i = blockIdx.z >> 2, sk = blockIdx.z & 3;
  int kb = sk * 320;
  int ke = kb + 320 < M_ ? kb + 320 : M_;
  gemm_tile_body<float, false, false>(
      inside16 + (size_t)i * A_ * M_, M_, A_,
      kT16 + (size_t)i * D_ * M_, M_,
      nullptr, nullptr,
      partial + (size_t)(sk * N_ + i) * A_ * D_, D_,
      blockIdx.x * 64, blockIdx.y * 64, kb, ke);
}

// ---------------- agg reduce + q-input prep + lam projection ----------------
__global__ __launch_bounds__(256) void agg_reduce(const float* __restrict__ partial,
                                                  const float* __restrict__ b_feature,
                                                  const float* __restrict__ anchor_embed,
                                                  const float* __restrict__ lam_w,
                                                  const float* __restrict__ lam_b,
                                                  float* __restrict__ bf_upd,
                                                  _Float16* __restrict__ qin16,
                                                  float* __restrict__ lm_rm) {
  int wid = threadIdx.x >> 6, lane = threadIdx.x & 63;
  int rg = blockIdx.x * 4 + wid;   // 0..4499
  int d0 = lane * 4;
  float lw[4][8];
#pragma unroll
  for (int e = 0; e < 4; e++) {
#pragma unroll
    for (int h = 0; h < 8; h++) lw[e][h] = lam_w[(d0 + e) * 8 + h];
  }
  float4 s = *(const float4*)&partial[(size_t)rg * D_ + d0];
#pragma unroll
  for (int sk = 1; sk < 4; sk++) {
    float4 p = *(const float4*)&partial[((size_t)sk * N_ * A_ + rg) * D_ + d0];
    s.x += p.x; s.y += p.y; s.z += p.z; s.w += p.w;
  }
  float4 bf = *(const float4*)&b_feature[(size_t)rg * D_ + d0];
  s.x += bf.x; s.y += bf.y; s.z += bf.z; s.w += bf.w;
  *(float4*)&bf_upd[(size_t)rg * D_ + d0] = s;
  float4 ae = *(const float4*)&anchor_embed[(size_t)rg * D_ + d0];
  f16x4 q4;
  q4[0] = (_Float16)(s.x + ae.x); q4[1] = (_Float16)(s.y + ae.y);
  q4[2] = (_Float16)(s.z + ae.z); q4[3] = (_Float16)(s.w + ae.w);
  *(f16x4*)&qin16[(size_t)rg * D_ + d0] = q4;
  float sv[4] = {s.x, s.y, s.z, s.w};
  float acc[8] = {};
#pragma unroll
  for (int e = 0; e < 4; e++)
#pragma unroll
    for (int h = 0; h < 8; h++) acc[h] += sv[e] * lw[e][h];
#pragma unroll
  for (int h = 0; h < 8; h++) {
#pragma unroll
    for (int o = 32; o; o >>= 1) acc[h] += __shfl_xor(acc[h], o, 64);
  }
  if (lane == 0) {
#pragma unroll
    for (int h = 0; h < 8; h++) lm_rm[(size_t)rg * H_ + h] = acc[h] + lam_b[h];
  }
}

// ---------------- fused q/k/v projections (one launch) ----------------
__global__ __launch_bounds__(256) void qkv_kernel(const _Float16* __restrict__ qA,
                                                  const _Float16* __restrict__ kA,
                                                  const _Float16* __restrict__ vA,
                                                  const _Float16* __restrict__ wT,   // [4][256][256] q,k,v,o
                                                  const float* __restrict__ bq,
                                                  const float* __restrict__ bk,
                                                  const float* __restrict__ bv,
                                                  _Float16* __restrict__ qC,
                                                  _Float16* __restrict__ kC,
                                                  _Float16* __restrict__ vC) {
  int bid = blockIdx.x;
  const _Float16 *Ap, *Bp;
  const float* bias;
  _Float16* Cp;
  int Mr, t, mt, nt;
  if (bid < 284)      { Ap = qA; Bp = wT;                 bias = bq; Cp = qC; Mr = 4500; t = bid;       mt = t % 71; nt = t / 71; }
  else if (bid < 660) { Ap = kA; Bp = wT + D_ * D_;       bias = bk; Cp = kC; Mr = 6000; t = bid - 284; mt = t % 94; nt = t / 94; }
  else                { Ap = vA; Bp = wT + 2 * D_ * D_;   bias = bv; Cp = vC; Mr = 6000; t = bid - 660; mt = t % 94; nt = t / 94; }
  gemm_tile_body<_Float16, true, false>(Ap, D_, Mr, Bp, D_, bias, nullptr, Cp, D_, mt * 64, nt * 64, 0, D_);
}

// ---------------- out projection + residual ----------------
__global__ __launch_bounds__(256) void outp_kernel(const _Float16* __restrict__ att16,
                                                   const _Float16* __restrict__ woT,
                                                   const float* __restrict__ bo,
                                                   const float* __restrict__ resid,
                                                   float* __restrict__ outb) {
  int bid = blockIdx.x;
  int mt = bid % 71, nt = bid / 71;
  gemm_tile_body<float, true, true>(att16, D_, 4500, woT, D_, bo, resid, outb, D_, mt * 64, nt * 64, 0, D_);
}

// ---------------- MFMA flash attention ----------------
__global__ __launch_bounds__(256) void attn_mfma(const _Float16* __restrict__ qh16,
                                                 const _Float16* __restrict__ kh16,
                                                 const _Float16* __restrict__ vh16,
                                                 const float* __restrict__ lm_rm,
                                                 const float* __restrict__ ban,
                                                 const float* __restrict__ i2j_rm,
                                                 _Float16* __restrict__ out) {
  int qt = blockIdx.x;
  int ih = blockIdx.y;
  int i = ih >> 3, h = ih & 7;
  int a0 = qt * 64;

  __shared__ _Float16 Qs[64][40];
  __shared__ _Float16 Ks[64][40];
  __shared__ _Float16 Vt[32][72];
  __shared__ _Float16 Ps[64][72];
  __shared__ float axs[64], ays[64], lmvs[64], cxs[64], cys[64];

  int tid = threadIdx.x;
  int lane = tid & 63;
  int w16 = (tid >> 6) * 16;
  int lr = lane & 15;
  int lk = (lane >> 4) * 8;
  int srow = tid >> 2, spiece = tid & 3;

  {
    int aq = a0 + srow;
    int a_ld = aq < A_ ? aq : A_ - 1;
    const uint4* src = (const uint4*)(qh16 + ((long)(i * A_ + a_ld) * D_ + h * DH_));
    *(uint4*)&Qs[srow][spiece * 8] = src[spiece];
  }
  if (tid < 64) {
    int aq = a0 + tid;
    int a_ld = aq < A_ ? aq : A_ - 1;
    axs[tid] = ban[(long)(i * A_ + a_ld) * AD_ + 0];
    ays[tid] = ban[(long)(i * A_ + a_ld) * AD_ + 1];
    lmvs[tid] = lm_rm[(long)(i * A_ + a_ld) * H_ + h];
  }
  __syncthreads();

  float axr[4], ayr[4], lmr[4];
#pragma unroll
  for (int r = 0; r < 4; r++) {
    int qrow = w16 + (lane >> 4) * 4 + r;
    axr[r] = axs[qrow]; ayr[r] = ays[qrow]; lmr[r] = lmvs[qrow];
  }
  f16x8 qa = *(const f16x8*)&Qs[w16 + lr][lk];

  float m_run[4], s_part[4];
  f32x4 oacc[2] = {};
#pragma unroll
  for (int r = 0; r < 4; r++) { m_run[r] = -INFINITY; s_part[r] = 0.0f; }

  const _Float16* kb = kh16 + (long)i * M_ * D_ + h * DH_;
  const _Float16* vb = vh16 + (long)i * M_ * D_ + h * DH_;

  for (int c = 0; c < NCHUNK_; c++) {
    int m0 = c * KC_;
    __syncthreads();
    {
      int mrow = m0 + srow;
      uint4 kv, vv;
      if (mrow < M_) {
        kv = ((const uint4*)(kb + (long)mrow * D_))[spiece];
        vv = ((const uint4*)(vb + (long)mrow * D_))[spiece];
      } else {
        kv = make_uint4(0, 0, 0, 0);
        vv = make_uint4(0, 0, 0, 0);
      }
      *(uint4*)&Ks[srow][spiece * 8] = kv;
      const _Float16* hp = (const _Float16*)&vv;
#pragma unroll
      for (int e = 0; e < 8; e++) Vt[spiece * 8 + e][srow] = hp[e];
    }
    if (tid < 64) {
      int mr = m0 + tid;
      int mc = mr < M_ ? mr : M_ - 1;
      cxs[tid] = i2j_rm[((long)i * M_ + mc) * AD_ + 0];
      cys[tid] = i2j_rm[((long)i * M_ + mc) * AD_ + 1];
    }
    __syncthreads();

    f32x4 sacc[4];
#pragma unroll
    for (int mb = 0; mb < 4; mb++) {
      f16x8 kf = *(const f16x8*)&Ks[mb * 16 + lr][lk];
      sacc[mb] = __builtin_amdgcn_mfma_f32_16x16x32_f16(qa, kf, (f32x4){0.f, 0.f, 0.f, 0.f}, 0, 0, 0);
    }

    float lg[4][4];
#pragma unroll
    for (int mb = 0; mb < 4; mb++) {
      int mcol = m0 + mb * 16 + (lane & 15);
      float cx = cxs[mb * 16 + (lane & 15)];
      float cy = cys[mb * 16 + (lane & 15)];
      bool valid = (mcol < M_);
#pragma unroll
      for (int r = 0; r < 4; r++) {
        float dx = axr[r] - cx, dy = ayr[r] - cy;
        float L = __logf(1.0f + sqrtf(dx * dx + dy * dy + 1e-12f));
        float v = sacc[mb][r] * 0.17677669529663687f - L * lmr[r];
        lg[mb][r] = valid ? v : -INFINITY;
      }
    }
#pragma unroll
    for (int r = 0; r < 4; r++) {
      float cm = fmaxf(fmaxf(lg[0][r], lg[1][r]), fmaxf(lg[2][r], lg[3][r]));
#pragma unroll
      for (int o = 1; o < 16; o <<= 1) cm = fmaxf(cm, __shfl_xor(cm, o, 64));
      float nm = fmaxf(m_run[r], cm);
      float corr = __expf(m_run[r] - nm);
      s_part[r] *= corr;
      oacc[0][r] *= corr;
      oacc[1][r] *= corr;
      m_run[r] = nm;
      float ps = 0.0f;
#pragma unroll
      for (int mb = 0; mb < 4; mb++) {
        float p = __expf(lg[mb][r] - nm);
        ps += p;
        Ps[w16 + (lane >> 4) * 4 + r][mb * 16 + (lane & 15)] = (_Float16)p;
      }
      s_part[r] += ps;
    }

#pragma unroll
    for (int ks = 0; ks < 2; ks++) {
      f16x8 pa = *(const f16x8*)&Ps[w16 + lr][ks * 32 + lk];
#pragma unroll
      for (int db = 0; db < 2; db++) {
        f16x8 vf = *(const f16x8*)&Vt[db * 16 + lr][ks * 32 + lk];
        oacc[db] = __builtin_amdgcn_mfma_f32_16x16x32_f16(pa, vf, oacc[db], 0, 0, 0);
      }
    }
  }

  float inv[4];
#pragma unroll
  for (int r = 0; r < 4; r++) {
    float st = s_part[r];
#pragma unroll
    for (int o = 1; o < 16; o <<= 1) st += __shfl_xor(st, o, 64);
    inv[r] = 1.0f / st;
  }
#pragma unroll
  for (int db = 0; db < 2; db++) {
#pragma unroll
    for (int r = 0; r < 4; r++) {
      int a = a0 + w16 + (lane >> 4) * 4 + r;
      if (a < A_) out[((long)(i * A_ + a)) * D_ + h * DH_ + db * 16 + (lane & 15)] =
          (_Float16)(oacc[db][r] * inv[r]);
    }
  }
}

// ---------------- LayerNorm ----------------
__global__ __launch_bounds__(256) void ln_kernel(const float* __restrict__ x,
                                                 const float* __restrict__ g,
                                                 const float* __restrict__ b,
                                                 float* __restrict__ out) {
  int row = blockIdx.x;
  int t = threadIdx.x;
  float v = x[(long)row * D_ + t];
  float s = v, sq = v * v;
#pragma unroll
  for (int o = 32; o; o >>= 1) {
    s += __shfl_xor(s, o, 64);
    sq += __shfl_xor(sq, o, 64);
  }
  __shared__ float ss[4], ssq[4];
  int wid = t >> 6, lane = t & 63;
  if (lane == 0) { ss[wid] = s; ssq[wid] = sq; }
  __syncthreads();
  float ts = ss[0] + ss[1] + ss[2] + ss[3];
  float tq = ssq[0] + ssq[1] + ssq[2] + ssq[3];
  float mean = ts / (float)D_;
  float var = tq / (float)D_ - mean * mean;
  out[(long)row * D_ + t] = (v - mean) * rsqrtf(var + 1e-5f) * g[t] + b[t];
}

extern "C" void kernel_launch(void* const* d_in, const int* in_sizes, int n_in,
                              void* d_out, int out_size, void* d_ws, size_t ws_size,
                              hipStream_t stream) {
  const float* i2j_anchor   = (const float*)d_in[0];
  const float* b_anchor     = (const float*)d_in[1];
  const float* b_feature    = (const float*)d_in[2];
  const float* tm           = (const float*)d_in[3];
  const float* anchor_embed = (const float*)d_in[4];
  const float* w_roi  = (const float*)d_in[5];
  const float* b_roi  = (const float*)d_in[6];
  const float* bn_g   = (const float*)d_in[7];
  const float* bn_b   = (const float*)d_in[8];
  const float* fc1_w  = (const float*)d_in[9];
  const float* fc1_b  = (const float*)d_in[10];
  const float* fc2_w  = (const float*)d_in[11];
  const float* fc2_b  = (const float*)d_in[12];
  const float* anc_w  = (const float*)d_in[13];
  const float* anc_b  = (const float*)d_in[14];
  const float* lam_w  = (const float*)d_in[15];
  const float* lam_b  = (const float*)d_in[16];
  const float* wq = (const float*)d_in[17];
  const float* bq = (const float*)d_in[18];
  const float* wk = (const float*)d_in[19];
  const float* bk = (const float*)d_in[20];
  const float* wv = (const float*)d_in[21];
  const float* bv = (const float*)d_in[22];
  const float* wo = (const float*)d_in[23];
  const float* bo = (const float*)d_in[24];
  const float* ln_g = (const float*)d_in[25];
  const float* ln_b = (const float*)d_in[26];

  float* ws = (float*)d_ws;
  size_t off = 0;
  auto alloc = [&](size_t n) { float* p = ws + off; off += (n + 3) & ~(size_t)3; return p; };

  float* scores     = alloc(N_ * A_);
  int*   top_idx    = (int*)alloc(N_ * K_);
  float* conf       = alloc(N_ * K_);
  float* t_mlp      = alloc(20 * D_);
  float* conf_rm    = alloc((size_t)N_ * M_);
  float* i2j_rm     = alloc((size_t)N_ * M_ * AD_);
  _Float16* key_feat16 = (_Float16*)alloc((size_t)N_ * M_ * D_ / 2);
  _Float16* key_in16   = (_Float16*)alloc((size_t)N_ * M_ * D_ / 2);
  _Float16* kT16       = (_Float16*)alloc((size_t)N_ * D_ * M_ / 2);
  _Float16* inside16   = (_Float16*)alloc((size_t)N_ * A_ * M_ / 2);
  _Float16* wT16       = (_Float16*)alloc((size_t)4 * D_ * D_ / 2);
  float* partial    = alloc((size_t)4 * N_ * A_ * D_);
  float* bf_upd     = alloc((size_t)N_ * A_ * D_);
  _Float16* qin16   = (_Float16*)alloc((size_t)N_ * A_ * D_ / 2);
  _Float16* qh16    = (_Float16*)alloc((size_t)N_ * A_ * D_ / 2);
  _Float16* kh16    = (_Float16*)alloc((size_t)N_ * M_ * D_ / 2);
  _Float16* vh16    = (_Float16*)alloc((size_t)N_ * M_ * D_ / 2);
  float* lm_rm      = alloc((size_t)N_ * A_ * H_);
  _Float16* att16   = (_Float16*)alloc((size_t)N_ * A_ * D_ / 2);
  float* res_buf    = alloc((size_t)N_ * A_ * D_);

  // 0. weight transposes (no deps)
  wtrans_kernel<<<dim3(16, 4), 256, 0, stream>>>(wq, wk, wv, wo, wT16);
  // 1. scores
  score_kernel<<<(N_ * A_ + 3) / 4, 256, 0, stream>>>(b_feature, w_roi, b_roi, scores);
  // 2. top-k
  topk_kernel<<<N_, 1024, 0, stream>>>(scores, top_idx, conf);
  // 3. tiny MLP
  mlp_kernel<<<20, 256, 0, stream>>>(tm, bn_g, bn_b, fc1_w, fc1_b, fc2_w, fc2_b, t_mlp);
  // 4. gather (fp16 outputs)
  gather_kernel<<<dim3(N_ * NM1_, K_ / GKT_), 256, 0, stream>>>(b_feature, i2j_anchor, top_idx, conf,
                                                                anc_w, anc_b, t_mlp,
                                                                key_feat16, conf_rm, i2j_rm, key_in16);
  // 5. key_feat transpose
  kftrans_kernel<<<dim3(19, 4, N_), 256, 0, stream>>>(key_feat16, kT16);
  // 6. inside mask
  inside_kernel<<<N_ * A_, 256, 0, stream>>>(i2j_rm, conf_rm, b_anchor, inside16);
  // 7. agg GEMM split-K (1200 blocks)
  agg_kernel<<<dim3(15, 4, N_ * 4), 256, 0, stream>>>(inside16, kT16, partial);
  // 8. reduce + qin + lam
  agg_reduce<<<(N_ * A_) / 4, 256, 0, stream>>>(partial, b_feature, anchor_embed, lam_w, lam_b,
                                                bf_upd, qin16, lm_rm);
  // 9. fused q/k/v projections (1036 blocks)
  qkv_kernel<<<284 + 376 + 376, 256, 0, stream>>>(qin16, key_in16, key_feat16, wT16,
                                                  bq, bk, bv, qh16, kh16, vh16);
  // 10. attention
  attn_mfma<<<dim3(15, N_ * H_), 256, 0, stream>>>(qh16, kh16, vh16, lm_rm, b_anchor, i2j_rm, att16);
  // 11. out projection + residual
  outp_kernel<<<284, 256, 0, stream>>>(att16, wT16 + 3 * D_ * D_, bo, bf_upd, res_buf);
  // 12. LayerNorm
  ln_kernel<<<N_ * A_, 256, 0, stream>>>(res_buf, ln_g, ln_b, (float*)d_out);
}